// Round 6
// baseline (920.584 us; speedup 1.0000x reference)
//
#include <hip/hip_runtime.h>

#define DD 64
#define POOL_NPB 512  // nodes per block in pool_head2

// f32 -> bf16 (RNE), result in low 16 bits
__device__ __forceinline__ unsigned f2bf(float x) {
  unsigned u = __float_as_uint(x);
  return (u + 0x7fffu + ((u >> 16) & 1u)) >> 16;
}

// ================= CSR build =================
__global__ __launch_bounds__(256) void k_deg(const int* __restrict__ dst,
                                             int* __restrict__ deg, int E) {
  int e = blockIdx.x * 256 + threadIdx.x;
  if (e < E) atomicAdd(&deg[dst[e]], 1);
}

__global__ __launch_bounds__(256) void k_scan1(const int* __restrict__ deg,
                                               int* __restrict__ partials,
                                               int N) {
  __shared__ int s[256];
  const int t = threadIdx.x;
  const int i = blockIdx.x * 256 + t;
  s[t] = (i < N) ? deg[i] : 0;
  __syncthreads();
#pragma unroll
  for (int off = 128; off > 0; off >>= 1) {
    if (t < off) s[t] += s[t + off];
    __syncthreads();
  }
  if (t == 0) partials[blockIdx.x] = s[0];
}

__global__ __launch_bounds__(256) void k_scan2(int* __restrict__ partials,
                                               int nb) {
  __shared__ int s[256];
  const int t = threadIdx.x;
  const int v = (t < nb) ? partials[t] : 0;
  s[t] = v;
  __syncthreads();
#pragma unroll
  for (int off = 1; off < 256; off <<= 1) {
    const int add = (t >= off) ? s[t - off] : 0;
    __syncthreads();
    s[t] += add;
    __syncthreads();
  }
  if (t < nb) partials[t] = s[t] - v;  // exclusive
}

__global__ __launch_bounds__(256) void k_scan3(const int* __restrict__ deg,
                                               const int* __restrict__ partials,
                                               int* __restrict__ rowptr,
                                               int* __restrict__ cursor, int N,
                                               int E) {
  __shared__ int s[256];
  const int t = threadIdx.x;
  const int i = blockIdx.x * 256 + t;
  const int v = (i < N) ? deg[i] : 0;
  s[t] = v;
  __syncthreads();
#pragma unroll
  for (int off = 1; off < 256; off <<= 1) {
    const int add = (t >= off) ? s[t - off] : 0;
    __syncthreads();
    s[t] += add;
    __syncthreads();
  }
  if (i < N) {
    const int ex = partials[blockIdx.x] + s[t] - v;
    rowptr[i] = ex;
    cursor[i] = ex;
    if (i == N - 1) rowptr[N] = E;
  }
}

__global__ __launch_bounds__(256) void k_fill(const int* __restrict__ src,
                                              const int* __restrict__ dst,
                                              const int* __restrict__ et,
                                              int* __restrict__ cursor,
                                              int* __restrict__ srcet, int E) {
  int e = blockIdx.x * 256 + threadIdx.x;
  if (e >= E) return;
  int pos = atomicAdd(&cursor[dst[e]], 1);
  srcet[pos] = (src[e] << 2) | et[e];
}

// ================= f32 -> bf16 feature conversion =================
__global__ __launch_bounds__(256) void conv_bf16(const float* __restrict__ x,
                                                 ushort* __restrict__ xb,
                                                 int n4) {
  int i = blockIdx.x * 256 + threadIdx.x;  // one float4 per thread
  if (i < n4) {
    float4 v = ((const float4*)x)[i];
    uint2 o;
    o.x = f2bf(v.x) | (f2bf(v.y) << 16);
    o.y = f2bf(v.z) | (f2bf(v.w) << 16);
    ((uint2*)xb)[i] = o;
  }
}

// ================= per-node relation gather (bf16 rows, 8 edges in flight) ====
__global__ __launch_bounds__(256) void gather_rel_b(
    const ushort* __restrict__ hb, const int* __restrict__ rowptr,
    const int* __restrict__ srcet, float* __restrict__ aggr, int N) {
  const int n = blockIdx.x * 4 + (threadIdx.x >> 6);
  const int lane = threadIdx.x & 63;
  const int g = lane >> 3;  // edge slot 0..7
  const int t = lane & 7;   // 16B chunk (8 bf16 values)
  if (n >= N) return;
  const int beg = rowptr[n], end = rowptr[n + 1];

  float a0[8], a1[8], a2[8], a3[8];
#pragma unroll
  for (int k = 0; k < 8; ++k) { a0[k] = 0.f; a1[k] = 0.f; a2[k] = 0.f; a3[k] = 0.f; }

  for (int j = beg + g; j < end; j += 8) {
    const int se = srcet[j];  // 8 lanes same addr -> broadcast
    const int s = se >> 2;
    const int r = se & 3;
    const uint4 raw = *(const uint4*)(hb + ((size_t)s << 6) + (t << 3));
    float v[8];
    v[0] = __uint_as_float(raw.x << 16);
    v[1] = __uint_as_float(raw.x & 0xffff0000u);
    v[2] = __uint_as_float(raw.y << 16);
    v[3] = __uint_as_float(raw.y & 0xffff0000u);
    v[4] = __uint_as_float(raw.z << 16);
    v[5] = __uint_as_float(raw.z & 0xffff0000u);
    v[6] = __uint_as_float(raw.w << 16);
    v[7] = __uint_as_float(raw.w & 0xffff0000u);
    if (r == 0) {
#pragma unroll
      for (int k = 0; k < 8; ++k) a0[k] += v[k];
    } else if (r == 1) {
#pragma unroll
      for (int k = 0; k < 8; ++k) a1[k] += v[k];
    } else if (r == 2) {
#pragma unroll
      for (int k = 0; k < 8; ++k) a2[k] += v[k];
    } else {
#pragma unroll
      for (int k = 0; k < 8; ++k) a3[k] += v[k];
    }
  }

#pragma unroll
  for (int off = 8; off <= 32; off <<= 1) {
#pragma unroll
    for (int k = 0; k < 8; ++k) {
      a0[k] += __shfl_xor(a0[k], off);
      a1[k] += __shfl_xor(a1[k], off);
      a2[k] += __shfl_xor(a2[k], off);
      a3[k] += __shfl_xor(a3[k], off);
    }
  }

  if (g < 4) {
    float r8[8];
    if (g == 0) {
#pragma unroll
      for (int k = 0; k < 8; ++k) r8[k] = a0[k];
    } else if (g == 1) {
#pragma unroll
      for (int k = 0; k < 8; ++k) r8[k] = a1[k];
    } else if (g == 2) {
#pragma unroll
      for (int k = 0; k < 8; ++k) r8[k] = a2[k];
    } else {
#pragma unroll
      for (int k = 0; k < 8; ++k) r8[k] = a3[k];
    }
    float* o = aggr + ((size_t)n << 8) + (g << 6) + (t << 3);
    *(float4*)(o + 0) = make_float4(r8[0], r8[1], r8[2], r8[3]);
    *(float4*)(o + 4) = make_float4(r8[4], r8[5], r8[6], r8[7]);
  }
}

// ======= dense: hb_out = bf16(relu(sum_r aggr[r]@Wrel[r] + hb_in@Wloop + brel)) ======
__global__ __launch_bounds__(256) void rgcn_dense_b(
    const float* __restrict__ aggr, const ushort* __restrict__ hb_in,
    const float* __restrict__ Wrel, const float* __restrict__ Wloop,
    const float* __restrict__ brel, ushort* __restrict__ hb_out, int N) {
  const int lane = threadIdx.x & 63;
  const int wv = threadIdx.x >> 6;
  const int c0 = __builtin_amdgcn_readfirstlane(wv << 4);
  const int n = blockIdx.x * 64 + lane;

  float acc[16];
#pragma unroll
  for (int jj = 0; jj < 16; ++jj) acc[jj] = brel[c0 + jj];

  float in[DD];
#pragma unroll 1
  for (int m = 0; m < 5; ++m) {
    const float* __restrict__ W =
        (m < 4) ? (Wrel + (size_t)m * DD * DD) : Wloop;
    if (n < N) {
      if (m < 4) {
        const float4* p = (const float4*)(aggr + ((size_t)n << 8) + (m << 6));
#pragma unroll
        for (int t = 0; t < DD / 4; ++t) {
          float4 v = p[t];
          in[4 * t + 0] = v.x; in[4 * t + 1] = v.y;
          in[4 * t + 2] = v.z; in[4 * t + 3] = v.w;
        }
      } else {
        const uint4* p = (const uint4*)(hb_in + ((size_t)n << 6));
#pragma unroll
        for (int q = 0; q < 8; ++q) {
          const uint4 raw = p[q];
          in[8 * q + 0] = __uint_as_float(raw.x << 16);
          in[8 * q + 1] = __uint_as_float(raw.x & 0xffff0000u);
          in[8 * q + 2] = __uint_as_float(raw.y << 16);
          in[8 * q + 3] = __uint_as_float(raw.y & 0xffff0000u);
          in[8 * q + 4] = __uint_as_float(raw.z << 16);
          in[8 * q + 5] = __uint_as_float(raw.z & 0xffff0000u);
          in[8 * q + 6] = __uint_as_float(raw.w << 16);
          in[8 * q + 7] = __uint_as_float(raw.w & 0xffff0000u);
        }
      }
    } else {
#pragma unroll
      for (int t = 0; t < DD; ++t) in[t] = 0.f;
    }
#pragma unroll
    for (int k = 0; k < DD; ++k) {
      const float hk = in[k];
#pragma unroll
      for (int jj = 0; jj < 16; ++jj)
        acc[jj] = fmaf(hk, W[k * DD + c0 + jj], acc[jj]);
    }
  }
  if (n < N) {
    uint u[8];
#pragma unroll
    for (int jj = 0; jj < 8; ++jj) {
      const float x0 = fmaxf(acc[2 * jj + 0], 0.f);
      const float x1 = fmaxf(acc[2 * jj + 1], 0.f);
      u[jj] = f2bf(x0) | (f2bf(x1) << 16);
    }
    uint4* o = (uint4*)(hb_out + ((size_t)n << 6) + c0);
    o[0] = make_uint4(u[0], u[1], u[2], u[3]);
    o[1] = make_uint4(u[4], u[5], u[6], u[7]);
  }
}

// ======= GAT projection: zb = bf16(h@Wg); el/er fused (LDS cross-wave reduce) =====
__global__ __launch_bounds__(256) void gemm_gat(
    const ushort* __restrict__ hb_in, const float* __restrict__ Wg,
    const float* __restrict__ al, const float* __restrict__ ar,
    ushort* __restrict__ zb, float* __restrict__ el, float* __restrict__ er,
    int N) {
  __shared__ float sel[4][64];
  __shared__ float ser[4][64];
  const int lane = threadIdx.x & 63;
  const int wv = threadIdx.x >> 6;
  const int c0 = __builtin_amdgcn_readfirstlane(wv << 4);
  const int n = blockIdx.x * 64 + lane;

  float in[DD];
  if (n < N) {
    const uint4* p = (const uint4*)(hb_in + ((size_t)n << 6));
#pragma unroll
    for (int q = 0; q < 8; ++q) {
      const uint4 raw = p[q];
      in[8 * q + 0] = __uint_as_float(raw.x << 16);
      in[8 * q + 1] = __uint_as_float(raw.x & 0xffff0000u);
      in[8 * q + 2] = __uint_as_float(raw.y << 16);
      in[8 * q + 3] = __uint_as_float(raw.y & 0xffff0000u);
      in[8 * q + 4] = __uint_as_float(raw.z << 16);
      in[8 * q + 5] = __uint_as_float(raw.z & 0xffff0000u);
      in[8 * q + 6] = __uint_as_float(raw.w << 16);
      in[8 * q + 7] = __uint_as_float(raw.w & 0xffff0000u);
    }
  } else {
#pragma unroll
    for (int t = 0; t < DD; ++t) in[t] = 0.f;
  }

  float acc[16];
#pragma unroll
  for (int jj = 0; jj < 16; ++jj) acc[jj] = 0.f;
#pragma unroll
  for (int k = 0; k < DD; ++k) {
    const float hk = in[k];
#pragma unroll
    for (int jj = 0; jj < 16; ++jj)
      acc[jj] = fmaf(hk, Wg[k * DD + c0 + jj], acc[jj]);
  }

  // partial el/er over this wave's 16 columns
  float pl = 0.f, pr = 0.f;
#pragma unroll
  for (int jj = 0; jj < 16; ++jj) {
    pl = fmaf(acc[jj], al[c0 + jj], pl);
    pr = fmaf(acc[jj], ar[c0 + jj], pr);
  }
  sel[wv][lane] = pl;
  ser[wv][lane] = pr;
  __syncthreads();
  if (wv == 0 && n < N) {
    el[n] = sel[0][lane] + sel[1][lane] + sel[2][lane] + sel[3][lane];
    er[n] = ser[0][lane] + ser[1][lane] + ser[2][lane] + ser[3][lane];
  }

  if (n < N) {
    uint u[8];
#pragma unroll
    for (int jj = 0; jj < 8; ++jj)
      u[jj] = f2bf(acc[2 * jj + 0]) | (f2bf(acc[2 * jj + 1]) << 16);
    uint4* o = (uint4*)(zb + ((size_t)n << 6) + c0);
    o[0] = make_uint4(u[0], u[1], u[2], u[3]);
    o[1] = make_uint4(u[4], u[5], u[6], u[7]);
  }
}

// ================= fused GAT aggregation (bf16 z rows, 8 edges in flight) ========
__global__ __launch_bounds__(256) void gat_fused_b(
    const ushort* __restrict__ zb, const float* __restrict__ el,
    const float* __restrict__ er, const int* __restrict__ rowptr,
    const int* __restrict__ srcet, float* __restrict__ hg, int N) {
  const int n = blockIdx.x * 4 + (threadIdx.x >> 6);
  const int lane = threadIdx.x & 63;
  const int g = lane >> 3;
  const int t = lane & 7;
  if (n >= N) return;
  const int beg = rowptr[n], end = rowptr[n + 1];
  const float ern = er[n];

  // phase A: online (m, den) with 64 edges in flight
  float m = -1e30f, den = 0.f;
  for (int j = beg + lane; j < end; j += 64) {
    const int s = srcet[j] >> 2;
    float x = el[s] + ern;
    x = (x > 0.f) ? x : 0.2f * x;
    if (x > m) {
      den *= __expf(m - x);
      m = x;
    }
    den += __expf(x - m);
  }
#pragma unroll
  for (int off = 1; off < 64; off <<= 1) {
    float mo = __shfl_xor(m, off);
    float dn = __shfl_xor(den, off);
    float M = fmaxf(m, mo);
    den = den * __expf(m - M) + dn * __expf(mo - M);
    m = M;
  }

  // phase B: weighted gather, 8 edges in flight
  float num[8];
#pragma unroll
  for (int k = 0; k < 8; ++k) num[k] = 0.f;
  for (int j = beg + g; j < end; j += 8) {
    const int se = srcet[j];
    const int s = se >> 2;
    float x = el[s] + ern;
    x = (x > 0.f) ? x : 0.2f * x;
    const float w = __expf(x - m);
    const uint4 raw = *(const uint4*)(zb + ((size_t)s << 6) + (t << 3));
    num[0] = fmaf(w, __uint_as_float(raw.x << 16), num[0]);
    num[1] = fmaf(w, __uint_as_float(raw.x & 0xffff0000u), num[1]);
    num[2] = fmaf(w, __uint_as_float(raw.y << 16), num[2]);
    num[3] = fmaf(w, __uint_as_float(raw.y & 0xffff0000u), num[3]);
    num[4] = fmaf(w, __uint_as_float(raw.z << 16), num[4]);
    num[5] = fmaf(w, __uint_as_float(raw.z & 0xffff0000u), num[5]);
    num[6] = fmaf(w, __uint_as_float(raw.w << 16), num[6]);
    num[7] = fmaf(w, __uint_as_float(raw.w & 0xffff0000u), num[7]);
  }
#pragma unroll
  for (int off = 8; off <= 32; off <<= 1) {
#pragma unroll
    for (int k = 0; k < 8; ++k) num[k] += __shfl_xor(num[k], off);
  }
  if (g == 0) {
    const float inv = 1.f / fmaxf(den, 1e-9f);
    float* o = hg + ((size_t)n << 6) + (t << 3);
    *(float4*)(o + 0) =
        make_float4(num[0] * inv, num[1] * inv, num[2] * inv, num[3] * inv);
    *(float4*)(o + 4) =
        make_float4(num[4] * inv, num[5] * inv, num[6] * inv, num[7] * inv);
  }
}

// ================= pooled head, two-level (LDS per-gid table, sorted gids) =========
__global__ __launch_bounds__(256) void pool_head2(
    const float* __restrict__ hg, const float* __restrict__ Wd,
    const int* __restrict__ gids, float* __restrict__ out, int N, int B) {
  __shared__ float acc[1024];
  for (int i = threadIdx.x; i < B; i += 256) acc[i] = 0.f;
  __syncthreads();

  const int wv = threadIdx.x >> 6;
  const int lane = threadIdx.x & 63;
  const int sub = lane & 3;
  const int idx = lane >> 2;

  const float4 w0 = *(const float4*)(Wd + (sub << 4) + 0);
  const float4 w1 = *(const float4*)(Wd + (sub << 4) + 4);
  const float4 w2 = *(const float4*)(Wd + (sub << 4) + 8);
  const float4 w3 = *(const float4*)(Wd + (sub << 4) + 12);

  const int base0 = blockIdx.x * POOL_NPB;
#pragma unroll 1
  for (int it = 0; it < POOL_NPB / 64; ++it) {
    const int n = base0 + it * 64 + wv * 16 + idx;
    if (n < N) {
      const float* p = hg + ((size_t)n << 6) + (sub << 4);
      const float4 v0 = *(const float4*)(p + 0);
      const float4 v1 = *(const float4*)(p + 4);
      const float4 v2 = *(const float4*)(p + 8);
      const float4 v3 = *(const float4*)(p + 12);
      float s = v0.x * w0.x + v0.y * w0.y + v0.z * w0.z + v0.w * w0.w;
      s = fmaf(v1.x, w1.x, s); s = fmaf(v1.y, w1.y, s);
      s = fmaf(v1.z, w1.z, s); s = fmaf(v1.w, w1.w, s);
      s = fmaf(v2.x, w2.x, s); s = fmaf(v2.y, w2.y, s);
      s = fmaf(v2.z, w2.z, s); s = fmaf(v2.w, w2.w, s);
      s = fmaf(v3.x, w3.x, s); s = fmaf(v3.y, w3.y, s);
      s = fmaf(v3.z, w3.z, s); s = fmaf(v3.w, w3.w, s);
      s += __shfl_xor(s, 1);
      s += __shfl_xor(s, 2);
      if (sub == 0) atomicAdd(&acc[gids[n]], s);
    }
  }
  __syncthreads();
  for (int i = threadIdx.x; i < B; i += 256) {
    const float v = acc[i];
    if (v != 0.f) unsafeAtomicAdd(out + i, v);
  }
}

__global__ void init_out_k(float* out, const float* bd, int n) {
  int i = blockIdx.x * blockDim.x + threadIdx.x;
  if (i < n) out[i] = bd[0];
}

// ================= launch =================
extern "C" void kernel_launch(void* const* d_in, const int* in_sizes, int n_in,
                              void* d_out, int out_size, void* d_ws,
                              size_t ws_size, hipStream_t stream) {
  const float* h0 = (const float*)d_in[0];
  const float* Wrel = (const float*)d_in[1];
  const float* Wloop = (const float*)d_in[2];
  const float* brel = (const float*)d_in[3];
  const float* Wg = (const float*)d_in[4];
  const float* al = (const float*)d_in[5];
  const float* ar = (const float*)d_in[6];
  const float* Wd = (const float*)d_in[7];
  const float* bd = (const float*)d_in[8];
  const int* src = (const int*)d_in[9];
  const int* dst = (const int*)d_in[10];
  const int* et = (const int*)d_in[11];
  const int* gids = (const int*)d_in[12];

  const int N = in_sizes[0] / DD;
  const int E = in_sizes[9];
  const int L = in_sizes[2] / (DD * DD);
  float* out = (float*)d_out;

  // ---- workspace layout ----
  char* wsb = (char*)d_ws;
  ushort* hbA = (ushort*)wsb;                       // N*64 bf16
  ushort* hbB = hbA + (size_t)N * DD;               // N*64 bf16
  float* aggr = (float*)(hbB + (size_t)N * DD);     // N*256 f32
  int* rowptr = (int*)(aggr + (size_t)N * 4 * DD);  // N+1
  int* cursor = rowptr + N + 1;                     // N
  int* deg = cursor + N;                            // N
  int* srcet = deg + N;                             // E
  float* el = (float*)(srcet + E);                  // N
  float* er = el + N;                               // N
  int* partials = (int*)(er + N);                   // <=256
  float* hg = aggr;  // overlay: aggr dead after last dense

  dim3 b256(256);
  const int grid_dense = (N + 63) / 64;
  const int grid_e = (E + 255) / 256;
  const int grid_n4 = (N + 3) / 4;
  const int nb = (N + 255) / 256;

  hipLaunchKernelGGL(init_out_k, dim3((out_size + 255) / 256), b256, 0, stream,
                     out, bd, out_size);

  // ---- CSR build ----
  hipMemsetAsync(deg, 0, (size_t)N * 4, stream);
  hipLaunchKernelGGL(k_deg, dim3(grid_e), b256, 0, stream, dst, deg, E);
  hipLaunchKernelGGL(k_scan1, dim3(nb), b256, 0, stream, deg, partials, N);
  hipLaunchKernelGGL(k_scan2, dim3(1), b256, 0, stream, partials, nb);
  hipLaunchKernelGGL(k_scan3, dim3(nb), b256, 0, stream, deg, partials, rowptr,
                     cursor, N, E);
  hipLaunchKernelGGL(k_fill, dim3(grid_e), b256, 0, stream, src, dst, et,
                     cursor, srcet, E);

  // ---- h0 -> bf16 ----
  hipLaunchKernelGGL(conv_bf16, dim3((N * DD / 4 + 255) / 256), b256, 0, stream,
                     h0, hbA, N * DD / 4);

  // ---- RGCN layers (bf16 feature path, f32 accumulation) ----
  ushort* cur = hbA;
  ushort* nxt = hbB;
  for (int l = 0; l < L; ++l) {
    hipLaunchKernelGGL(gather_rel_b, dim3(grid_n4), b256, 0, stream, cur,
                       rowptr, srcet, aggr, N);
    hipLaunchKernelGGL(rgcn_dense_b, dim3(grid_dense), b256, 0, stream, aggr,
                       cur, Wrel + (size_t)l * 4 * DD * DD,
                       Wloop + (size_t)l * DD * DD, brel + (size_t)l * DD, nxt,
                       N);
    ushort* tmp = cur; cur = nxt; nxt = tmp;
  }

  // ---- GAT ----
  ushort* zb = nxt;  // free bf16 buffer
  hipLaunchKernelGGL(gemm_gat, dim3(grid_dense), b256, 0, stream, cur, Wg, al,
                     ar, zb, el, er, N);
  hipLaunchKernelGGL(gat_fused_b, dim3(grid_n4), b256, 0, stream, zb, el, er,
                     rowptr, srcet, hg, N);

  const int grid_pool = (N + POOL_NPB - 1) / POOL_NPB;
  hipLaunchKernelGGL(pool_head2, dim3(grid_pool), b256, 0, stream, hg, Wd, gids,
                     out, N, out_size);
}

// Round 7
// 808.429 us; speedup vs baseline: 1.1387x; 1.1387x over previous
//
#include <hip/hip_runtime.h>

#define DD 64
#define POOL_NPB 512
#define EPB 2048  // edges per block in fill pipeline

// ================= CSR build: deg + coarse histogram =================
__global__ __launch_bounds__(256) void k_deg2(const int* __restrict__ dst,
                                              int* __restrict__ deg,
                                              int* __restrict__ chist, int E) {
  __shared__ int lh[256];
  lh[threadIdx.x] = 0;
  __syncthreads();
  const int base = blockIdx.x * EPB;
#pragma unroll
  for (int k = 0; k < EPB / 256; ++k) {
    const int e = base + k * 256 + threadIdx.x;
    if (e < E) {
      const int d = dst[e];
      atomicAdd(&deg[d], 1);
      atomicAdd(&lh[d >> 8], 1);
    }
  }
  __syncthreads();
  const int v = lh[threadIdx.x];
  if (v) atomicAdd(&chist[threadIdx.x], v);
}

// ---- 3-phase device-wide exclusive scan of deg -> rowptr ----
__global__ __launch_bounds__(256) void k_scan1(const int* __restrict__ deg,
                                               int* __restrict__ partials,
                                               int N) {
  __shared__ int s[256];
  const int t = threadIdx.x;
  const int i = blockIdx.x * 256 + t;
  s[t] = (i < N) ? deg[i] : 0;
  __syncthreads();
#pragma unroll
  for (int off = 128; off > 0; off >>= 1) {
    if (t < off) s[t] += s[t + off];
    __syncthreads();
  }
  if (t == 0) partials[blockIdx.x] = s[0];
}

__global__ __launch_bounds__(256) void k_scan2(int* __restrict__ partials,
                                               int nb) {
  __shared__ int s[256];
  const int t = threadIdx.x;
  const int v = (t < nb) ? partials[t] : 0;
  s[t] = v;
  __syncthreads();
#pragma unroll
  for (int off = 1; off < 256; off <<= 1) {
    const int add = (t >= off) ? s[t - off] : 0;
    __syncthreads();
    s[t] += add;
    __syncthreads();
  }
  if (t < nb) partials[t] = s[t] - v;
}

__global__ __launch_bounds__(256) void k_scan3(const int* __restrict__ deg,
                                               const int* __restrict__ partials,
                                               int* __restrict__ rowptr, int N,
                                               int E) {
  __shared__ int s[256];
  const int t = threadIdx.x;
  const int i = blockIdx.x * 256 + t;
  const int v = (i < N) ? deg[i] : 0;
  s[t] = v;
  __syncthreads();
#pragma unroll
  for (int off = 1; off < 256; off <<= 1) {
    const int add = (t >= off) ? s[t - off] : 0;
    __syncthreads();
    s[t] += add;
    __syncthreads();
  }
  if (i < N) {
    rowptr[i] = partials[blockIdx.x] + s[t] - v;
    if (i == N - 1) rowptr[N] = E;
  }
}

// ---- scan of coarse histogram -> gcur (mutable) + cbase (stable) ----
__global__ __launch_bounds__(256) void cscan(const int* __restrict__ chist,
                                             int* __restrict__ gcur,
                                             int* __restrict__ cbase) {
  __shared__ int s[256];
  const int t = threadIdx.x;
  const int v = chist[t];
  s[t] = v;
  __syncthreads();
#pragma unroll
  for (int off = 1; off < 256; off <<= 1) {
    const int add = (t >= off) ? s[t - off] : 0;
    __syncthreads();
    s[t] += add;
    __syncthreads();
  }
  const int ex = s[t] - v;
  gcur[t] = ex;
  cbase[t] = ex;
}

// ---- coarse scatter: LDS-reordered, bucket-contiguous 8B record runs ----
__global__ __launch_bounds__(256) void f2_coarse(
    const int* __restrict__ src, const int* __restrict__ dst,
    const int* __restrict__ et, int* __restrict__ gcur,
    uint2* __restrict__ staging, int E) {
  __shared__ int lcnt[256];
  __shared__ int sc[256];
  __shared__ int lbase[256];
  __shared__ int gb[256];
  __shared__ uint2 rec[EPB];

  const int t = threadIdx.x;
  const int base = blockIdx.x * EPB;
  const int bc = min(EPB, E - base);

  lcnt[t] = 0;
  __syncthreads();

  int d_[EPB / 256], se_[EPB / 256], rk_[EPB / 256];
#pragma unroll
  for (int k = 0; k < EPB / 256; ++k) {
    const int e = base + k * 256 + t;
    if (e < E) {
      const int d = dst[e];
      d_[k] = d;
      se_[k] = (src[e] << 2) | et[e];
      rk_[k] = atomicAdd(&lcnt[d >> 8], 1);
    } else {
      d_[k] = -1;
    }
  }
  __syncthreads();

  // exclusive scan lcnt -> lbase
  const int lv = lcnt[t];
  sc[t] = lv;
  __syncthreads();
#pragma unroll
  for (int off = 1; off < 256; off <<= 1) {
    const int add = (t >= off) ? sc[t - off] : 0;
    __syncthreads();
    sc[t] += add;
    __syncthreads();
  }
  lbase[t] = sc[t] - lv;
  // reserve global space for this block's buckets
  gb[t] = lv ? atomicAdd(&gcur[t], lv) : gcur[t];
  __syncthreads();

#pragma unroll
  for (int k = 0; k < EPB / 256; ++k) {
    if (d_[k] >= 0) {
      const int cb = d_[k] >> 8;
      rec[lbase[cb] + rk_[k]] = make_uint2((unsigned)d_[k], (unsigned)se_[k]);
    }
  }
  __syncthreads();

  for (int idx = t; idx < bc; idx += 256) {
    const uint2 r = rec[idx];
    const int cb = (int)(r.x >> 8);
    staging[gb[cb] + (idx - lbase[cb])] = r;
  }
}

// ---- fine placement: one block per coarse bucket, LDS cursors ----
__global__ __launch_bounds__(256) void f3_fine(
    const uint2* __restrict__ staging, const int* __restrict__ cbase,
    const int* __restrict__ rowptr, int* __restrict__ srcet, int N, int E,
    int ncb) {
  __shared__ int lcur[256];
  const int cb = blockIdx.x;
  const int t = threadIdx.x;
  const int d0 = cb << 8;
  const int dn = d0 + t;
  lcur[t] = (dn < N) ? rowptr[dn] : 0;
  __syncthreads();
  const int s0 = cbase[cb];
  const int s1 = (cb + 1 < ncb) ? cbase[cb + 1] : E;
  for (int i = s0 + t; i < s1; i += 256) {
    const uint2 r = staging[i];
    const int pos = atomicAdd(&lcur[r.x & 255u], 1);
    srcet[pos] = (int)r.y;
  }
}

// ================= per-node relation gather =================
__global__ __launch_bounds__(256) void gather_rel(
    const float* __restrict__ h, const int* __restrict__ rowptr,
    const int* __restrict__ srcet, float* __restrict__ aggr, int N,
    int relu_in) {
  const int n = blockIdx.x * 4 + (threadIdx.x >> 6);
  const int lane = threadIdx.x & 63;
  const int g = lane >> 4;    // edge slot 0..3
  const int t = lane & 15;    // float4 chunk 0..15
  if (n >= N) return;
  const int beg = rowptr[n], end = rowptr[n + 1];

  float4 a0 = make_float4(0.f, 0.f, 0.f, 0.f);
  float4 a1 = a0, a2 = a0, a3 = a0;

  for (int j = beg + g; j < end; j += 4) {
    const int se = srcet[j];
    const int s = se >> 2;
    const int r = se & 3;
    float4 v = *(const float4*)(h + ((size_t)s << 6) + (t << 2));
    if (relu_in) {
      v.x = fmaxf(v.x, 0.f); v.y = fmaxf(v.y, 0.f);
      v.z = fmaxf(v.z, 0.f); v.w = fmaxf(v.w, 0.f);
    }
    if (r == 0) { a0.x += v.x; a0.y += v.y; a0.z += v.z; a0.w += v.w; }
    else if (r == 1) { a1.x += v.x; a1.y += v.y; a1.z += v.z; a1.w += v.w; }
    else if (r == 2) { a2.x += v.x; a2.y += v.y; a2.z += v.z; a2.w += v.w; }
    else { a3.x += v.x; a3.y += v.y; a3.z += v.z; a3.w += v.w; }
  }

#pragma unroll
  for (int off = 16; off <= 32; off <<= 1) {
    a0.x += __shfl_xor(a0.x, off); a0.y += __shfl_xor(a0.y, off);
    a0.z += __shfl_xor(a0.z, off); a0.w += __shfl_xor(a0.w, off);
    a1.x += __shfl_xor(a1.x, off); a1.y += __shfl_xor(a1.y, off);
    a1.z += __shfl_xor(a1.z, off); a1.w += __shfl_xor(a1.w, off);
    a2.x += __shfl_xor(a2.x, off); a2.y += __shfl_xor(a2.y, off);
    a2.z += __shfl_xor(a2.z, off); a2.w += __shfl_xor(a2.w, off);
    a3.x += __shfl_xor(a3.x, off); a3.y += __shfl_xor(a3.y, off);
    a3.z += __shfl_xor(a3.z, off); a3.w += __shfl_xor(a3.w, off);
  }

  const float4 res = (g == 0) ? a0 : (g == 1) ? a1 : (g == 2) ? a2 : a3;
  *(float4*)(aggr + ((size_t)n << 8) + (g << 6) + (t << 2)) = res;
}

// ================= dense: hnext = sum_r aggr[r]@Wrel[r] + relu?(h)@Wloop + brel ==========
__global__ __launch_bounds__(256) void rgcn_dense(
    const float* __restrict__ aggr, const float* __restrict__ hin,
    const float* __restrict__ Wrel, const float* __restrict__ Wloop,
    const float* __restrict__ brel, float* __restrict__ hnext, int N,
    int relu_in) {
  const int lane = threadIdx.x & 63;
  const int wv = threadIdx.x >> 6;
  const int c0 = __builtin_amdgcn_readfirstlane(wv << 4);
  const int n = blockIdx.x * 64 + lane;

  float acc[16];
#pragma unroll
  for (int jj = 0; jj < 16; ++jj) acc[jj] = brel[c0 + jj];

  float in[DD];
#pragma unroll 1
  for (int m = 0; m < 5; ++m) {
    const float* __restrict__ W =
        (m < 4) ? (Wrel + (size_t)m * DD * DD) : Wloop;
    if (n < N) {
      const float4* p = (m < 4)
                            ? (const float4*)(aggr + ((size_t)n << 8) + (m << 6))
                            : (const float4*)(hin + ((size_t)n << 6));
#pragma unroll
      for (int t = 0; t < DD / 4; ++t) {
        float4 v = p[t];
        if (m == 4 && relu_in) {
          v.x = fmaxf(v.x, 0.f); v.y = fmaxf(v.y, 0.f);
          v.z = fmaxf(v.z, 0.f); v.w = fmaxf(v.w, 0.f);
        }
        in[4 * t + 0] = v.x; in[4 * t + 1] = v.y;
        in[4 * t + 2] = v.z; in[4 * t + 3] = v.w;
      }
    } else {
#pragma unroll
      for (int t = 0; t < DD; ++t) in[t] = 0.f;
    }
#pragma unroll
    for (int k = 0; k < DD; ++k) {
      const float hk = in[k];
#pragma unroll
      for (int jj = 0; jj < 16; ++jj)
        acc[jj] = fmaf(hk, W[k * DD + c0 + jj], acc[jj]);
    }
  }
  if (n < N) {
    float* o = hnext + ((size_t)n << 6) + c0;
#pragma unroll
    for (int jj = 0; jj < 16; jj += 4)
      *(float4*)(o + jj) =
          make_float4(acc[jj], acc[jj + 1], acc[jj + 2], acc[jj + 3]);
  }
}

// ================= z = relu(h) @ Wg =================
__global__ __launch_bounds__(256) void gemm_relu64(const float* __restrict__ hin,
                                                   const float* __restrict__ W,
                                                   float* __restrict__ out,
                                                   int N) {
  const int lane = threadIdx.x & 63;
  const int wv = threadIdx.x >> 6;
  const int c0 = __builtin_amdgcn_readfirstlane(wv << 4);
  const int n = blockIdx.x * 64 + lane;

  float h[DD];
  if (n < N) {
    const float4* hp = (const float4*)(hin + (size_t)n * DD);
#pragma unroll
    for (int t = 0; t < DD / 4; ++t) {
      float4 v = hp[t];
      v.x = fmaxf(v.x, 0.f); v.y = fmaxf(v.y, 0.f);
      v.z = fmaxf(v.z, 0.f); v.w = fmaxf(v.w, 0.f);
      h[4 * t + 0] = v.x; h[4 * t + 1] = v.y;
      h[4 * t + 2] = v.z; h[4 * t + 3] = v.w;
    }
  } else {
#pragma unroll
    for (int t = 0; t < DD; ++t) h[t] = 0.f;
  }
  float acc[16];
#pragma unroll
  for (int j = 0; j < 16; ++j) acc[j] = 0.f;
#pragma unroll
  for (int k = 0; k < DD; ++k) {
    const float hk = h[k];
#pragma unroll
    for (int j = 0; j < 16; ++j)
      acc[j] = fmaf(hk, W[k * DD + c0 + j], acc[j]);
  }
  if (n < N) {
    float* o = out + ((size_t)n << 6) + c0;
#pragma unroll
    for (int j = 0; j < 16; j += 4)
      *(float4*)(o + j) =
          make_float4(acc[j], acc[j + 1], acc[j + 2], acc[j + 3]);
  }
}

// ================= GAT: el/er per node =================
__global__ __launch_bounds__(256) void el_er_k(
    const float* __restrict__ z, const float* __restrict__ al,
    const float* __restrict__ ar, float* __restrict__ el,
    float* __restrict__ er, int N) {
  int n = blockIdx.x * 4 + (threadIdx.x >> 6);
  int lane = threadIdx.x & 63;
  if (n >= N) return;
  float v = z[(size_t)n * DD + lane];
  float pl = v * al[lane];
  float pr = v * ar[lane];
#pragma unroll
  for (int off = 32; off > 0; off >>= 1) {
    pl += __shfl_down(pl, off);
    pr += __shfl_down(pr, off);
  }
  if (lane == 0) {
    el[n] = pl;
    er[n] = pr;
  }
}

// ================= fused GAT aggregation =================
__global__ __launch_bounds__(256) void gat_fused(
    const float* __restrict__ z, const float* __restrict__ el,
    const float* __restrict__ er, const int* __restrict__ rowptr,
    const int* __restrict__ srcet, float* __restrict__ hg, int N) {
  const int n = blockIdx.x * 4 + (threadIdx.x >> 6);
  const int lane = threadIdx.x & 63;
  const int g = lane >> 4;
  const int t = lane & 15;
  if (n >= N) return;
  const int beg = rowptr[n], end = rowptr[n + 1];
  const float ern = er[n];

  float m = -1e30f, den = 0.f;
  for (int j = beg + lane; j < end; j += 64) {
    const int s = srcet[j] >> 2;
    float x = el[s] + ern;
    x = (x > 0.f) ? x : 0.2f * x;
    if (x > m) {
      den *= __expf(m - x);
      m = x;
    }
    den += __expf(x - m);
  }
#pragma unroll
  for (int off = 1; off < 64; off <<= 1) {
    float mo = __shfl_xor(m, off);
    float dn = __shfl_xor(den, off);
    float M = fmaxf(m, mo);
    den = den * __expf(m - M) + dn * __expf(mo - M);
    m = M;
  }

  float4 num = make_float4(0.f, 0.f, 0.f, 0.f);
  for (int j = beg + g; j < end; j += 4) {
    const int se = srcet[j];
    const int s = se >> 2;
    float x = el[s] + ern;
    x = (x > 0.f) ? x : 0.2f * x;
    const float w = __expf(x - m);
    float4 v = *(const float4*)(z + ((size_t)s << 6) + (t << 2));
    num.x = fmaf(w, v.x, num.x);
    num.y = fmaf(w, v.y, num.y);
    num.z = fmaf(w, v.z, num.z);
    num.w = fmaf(w, v.w, num.w);
  }
#pragma unroll
  for (int off = 16; off <= 32; off <<= 1) {
    num.x += __shfl_xor(num.x, off);
    num.y += __shfl_xor(num.y, off);
    num.z += __shfl_xor(num.z, off);
    num.w += __shfl_xor(num.w, off);
  }
  if (g == 0) {
    const float inv = 1.f / fmaxf(den, 1e-9f);
    float4 o = make_float4(num.x * inv, num.y * inv, num.z * inv, num.w * inv);
    *(float4*)(hg + ((size_t)n << 6) + (t << 2)) = o;
  }
}

// ================= pooled head, two-level =================
__global__ __launch_bounds__(256) void pool_head2(
    const float* __restrict__ hg, const float* __restrict__ Wd,
    const int* __restrict__ gids, float* __restrict__ out, int N, int B) {
  __shared__ float acc[1024];
  for (int i = threadIdx.x; i < B; i += 256) acc[i] = 0.f;
  __syncthreads();

  const int wv = threadIdx.x >> 6;
  const int lane = threadIdx.x & 63;
  const int sub = lane & 3;
  const int idx = lane >> 2;

  const float4 w0 = *(const float4*)(Wd + (sub << 4) + 0);
  const float4 w1 = *(const float4*)(Wd + (sub << 4) + 4);
  const float4 w2 = *(const float4*)(Wd + (sub << 4) + 8);
  const float4 w3 = *(const float4*)(Wd + (sub << 4) + 12);

  const int base0 = blockIdx.x * POOL_NPB;
#pragma unroll 1
  for (int it = 0; it < POOL_NPB / 64; ++it) {
    const int n = base0 + it * 64 + wv * 16 + idx;
    if (n < N) {
      const float* p = hg + ((size_t)n << 6) + (sub << 4);
      const float4 v0 = *(const float4*)(p + 0);
      const float4 v1 = *(const float4*)(p + 4);
      const float4 v2 = *(const float4*)(p + 8);
      const float4 v3 = *(const float4*)(p + 12);
      float s = v0.x * w0.x + v0.y * w0.y + v0.z * w0.z + v0.w * w0.w;
      s = fmaf(v1.x, w1.x, s); s = fmaf(v1.y, w1.y, s);
      s = fmaf(v1.z, w1.z, s); s = fmaf(v1.w, w1.w, s);
      s = fmaf(v2.x, w2.x, s); s = fmaf(v2.y, w2.y, s);
      s = fmaf(v2.z, w2.z, s); s = fmaf(v2.w, w2.w, s);
      s = fmaf(v3.x, w3.x, s); s = fmaf(v3.y, w3.y, s);
      s = fmaf(v3.z, w3.z, s); s = fmaf(v3.w, w3.w, s);
      s += __shfl_xor(s, 1);
      s += __shfl_xor(s, 2);
      if (sub == 0) atomicAdd(&acc[gids[n]], s);
    }
  }
  __syncthreads();
  for (int i = threadIdx.x; i < B; i += 256) {
    const float v = acc[i];
    if (v != 0.f) unsafeAtomicAdd(out + i, v);
  }
}

__global__ void init_out_k(float* out, const float* bd, int n) {
  int i = blockIdx.x * blockDim.x + threadIdx.x;
  if (i < n) out[i] = bd[0];
}

// ================= launch =================
extern "C" void kernel_launch(void* const* d_in, const int* in_sizes, int n_in,
                              void* d_out, int out_size, void* d_ws,
                              size_t ws_size, hipStream_t stream) {
  const float* h0 = (const float*)d_in[0];
  const float* Wrel = (const float*)d_in[1];
  const float* Wloop = (const float*)d_in[2];
  const float* brel = (const float*)d_in[3];
  const float* Wg = (const float*)d_in[4];
  const float* al = (const float*)d_in[5];
  const float* ar = (const float*)d_in[6];
  const float* Wd = (const float*)d_in[7];
  const float* bd = (const float*)d_in[8];
  const int* src = (const int*)d_in[9];
  const int* dst = (const int*)d_in[10];
  const int* et = (const int*)d_in[11];
  const int* gids = (const int*)d_in[12];

  const int N = in_sizes[0] / DD;
  const int E = in_sizes[9];
  const int L = in_sizes[2] / (DD * DD);
  float* out = (float*)d_out;

  // ---- workspace layout ----
  float* wsf = (float*)d_ws;
  float* hA = wsf;                          // N*64
  float* hB = hA + (size_t)N * DD;          // N*64
  float* aggr = hB + (size_t)N * DD;        // N*256
  int* rowptr = (int*)(aggr + (size_t)N * 4 * DD);  // N+1
  int* deg = rowptr + N + 1;                // N
  int* srcet = deg + N;                     // E
  float* el = (float*)(srcet + E);          // N
  float* er = el + N;                       // N
  int* partials = (int*)(er + N);           // 256
  int* chist = partials + 256;              // 256
  int* gcur = chist + 256;                  // 256
  int* cbase = gcur + 256;                  // 256
  uint2* staging = (uint2*)aggr;            // E uint2, overlays aggr (dead until layers)
  float* hg = aggr;                         // overlay: aggr dead after last dense

  dim3 b256(256);
  const int grid_dense = (N + 63) / 64;
  const int grid_n4 = (N + 3) / 4;
  const int nb = (N + 255) / 256;
  const int nfb = (E + EPB - 1) / EPB;
  const int ncb = (N + 255) >> 8;

  hipLaunchKernelGGL(init_out_k, dim3((out_size + 255) / 256), b256, 0, stream,
                     out, bd, out_size);

  // ---- CSR build (hierarchical fill) ----
  hipMemsetAsync(deg, 0, (size_t)N * 4, stream);
  hipMemsetAsync(chist, 0, 256 * 4, stream);
  hipLaunchKernelGGL(k_deg2, dim3(nfb), b256, 0, stream, dst, deg, chist, E);
  hipLaunchKernelGGL(k_scan1, dim3(nb), b256, 0, stream, deg, partials, N);
  hipLaunchKernelGGL(k_scan2, dim3(1), b256, 0, stream, partials, nb);
  hipLaunchKernelGGL(k_scan3, dim3(nb), b256, 0, stream, deg, partials, rowptr,
                     N, E);
  hipLaunchKernelGGL(cscan, dim3(1), b256, 0, stream, chist, gcur, cbase);
  hipLaunchKernelGGL(f2_coarse, dim3(nfb), b256, 0, stream, src, dst, et, gcur,
                     staging, E);
  hipLaunchKernelGGL(f3_fine, dim3(ncb), b256, 0, stream, staging, cbase,
                     rowptr, srcet, N, E, ncb);

  // ---- RGCN layers ----
  const float* cur = h0;
  float* nxt = hA;
  for (int l = 0; l < L; ++l) {
    hipLaunchKernelGGL(gather_rel, dim3(grid_n4), b256, 0, stream, cur, rowptr,
                       srcet, aggr, N, l > 0 ? 1 : 0);
    hipLaunchKernelGGL(rgcn_dense, dim3(grid_dense), b256, 0, stream, aggr, cur,
                       Wrel + (size_t)l * 4 * DD * DD,
                       Wloop + (size_t)l * DD * DD, brel + (size_t)l * DD, nxt,
                       N, l > 0 ? 1 : 0);
    cur = nxt;
    nxt = (cur == hA) ? hB : hA;
  }

  // ---- GAT ----
  float* zb = nxt;
  hipLaunchKernelGGL(gemm_relu64, dim3(grid_dense), b256, 0, stream, cur, Wg,
                     zb, N);
  hipLaunchKernelGGL(el_er_k, dim3(grid_n4), b256, 0, stream, zb, al, ar, el,
                     er, N);
  hipLaunchKernelGGL(gat_fused, dim3(grid_n4), b256, 0, stream, zb, el, er,
                     rowptr, srcet, hg, N);

  const int grid_pool = (N + POOL_NPB - 1) / POOL_NPB;
  hipLaunchKernelGGL(pool_head2, dim3(grid_pool), b256, 0, stream, hg, Wd, gids,
                     out, N, out_size);
}

// Round 8
// 752.135 us; speedup vs baseline: 1.2240x; 1.0748x over previous
//
#include <hip/hip_runtime.h>

#define DD 64
#define POOL_NPB 512
#define EPB 2048  // edges per block in fill pipeline

// ================= coarse histogram (LDS only) =================
__global__ __launch_bounds__(256) void k_hist(const int* __restrict__ dst,
                                              int* __restrict__ chist, int E) {
  __shared__ int lh[256];
  lh[threadIdx.x] = 0;
  __syncthreads();
  const int base = blockIdx.x * EPB;
#pragma unroll
  for (int k = 0; k < EPB / 256; ++k) {
    const int e = base + k * 256 + threadIdx.x;
    if (e < E) atomicAdd(&lh[dst[e] >> 8], 1);
  }
  __syncthreads();
  const int v = lh[threadIdx.x];
  if (v) atomicAdd(&chist[threadIdx.x], v);
}

// ---- scan of coarse histogram -> gcur (mutable) + cbase (stable) ----
__global__ __launch_bounds__(256) void cscan(const int* __restrict__ chist,
                                             int* __restrict__ gcur,
                                             int* __restrict__ cbase) {
  __shared__ int s[256];
  const int t = threadIdx.x;
  const int v = chist[t];
  s[t] = v;
  __syncthreads();
#pragma unroll
  for (int off = 1; off < 256; off <<= 1) {
    const int add = (t >= off) ? s[t - off] : 0;
    __syncthreads();
    s[t] += add;
    __syncthreads();
  }
  const int ex = s[t] - v;
  gcur[t] = ex;
  cbase[t] = ex;
}

// ---- coarse scatter: LDS-reordered, bucket-contiguous 8B record runs ----
__global__ __launch_bounds__(256) void f2_coarse(
    const int* __restrict__ src, const int* __restrict__ dst,
    const int* __restrict__ et, int* __restrict__ gcur,
    uint2* __restrict__ staging, int E) {
  __shared__ int lcnt[256];
  __shared__ int sc[256];
  __shared__ int lbase[256];
  __shared__ int gb[256];
  __shared__ uint2 rec[EPB];

  const int t = threadIdx.x;
  const int base = blockIdx.x * EPB;
  const int bc = min(EPB, E - base);

  lcnt[t] = 0;
  __syncthreads();

  int d_[EPB / 256], se_[EPB / 256], rk_[EPB / 256];
#pragma unroll
  for (int k = 0; k < EPB / 256; ++k) {
    const int e = base + k * 256 + t;
    if (e < E) {
      const int d = dst[e];
      d_[k] = d;
      se_[k] = (src[e] << 2) | et[e];
      rk_[k] = atomicAdd(&lcnt[d >> 8], 1);
    } else {
      d_[k] = -1;
    }
  }
  __syncthreads();

  // exclusive scan lcnt -> lbase
  const int lv = lcnt[t];
  sc[t] = lv;
  __syncthreads();
#pragma unroll
  for (int off = 1; off < 256; off <<= 1) {
    const int add = (t >= off) ? sc[t - off] : 0;
    __syncthreads();
    sc[t] += add;
    __syncthreads();
  }
  lbase[t] = sc[t] - lv;
  gb[t] = lv ? atomicAdd(&gcur[t], lv) : gcur[t];
  __syncthreads();

#pragma unroll
  for (int k = 0; k < EPB / 256; ++k) {
    if (d_[k] >= 0) {
      const int cb = d_[k] >> 8;
      rec[lbase[cb] + rk_[k]] = make_uint2((unsigned)d_[k], (unsigned)se_[k]);
    }
  }
  __syncthreads();

  for (int idx = t; idx < bc; idx += 256) {
    const uint2 r = rec[idx];
    const int cb = (int)(r.x >> 8);
    staging[gb[cb] + (idx - lbase[cb])] = r;
  }
}

// ---- fine placement: one block per coarse bucket. Derives rowptr locally:
//      rowptr[d] = cbase[cb] + exclusive_scan(local deg). ----
__global__ __launch_bounds__(256) void f3_fine2(
    const uint2* __restrict__ staging, const int* __restrict__ cbase,
    int* __restrict__ rowptr, int* __restrict__ srcet, int N, int E, int ncb) {
  __shared__ int ldeg[256];
  __shared__ int sc[256];
  __shared__ int lcur[256];
  const int cb = blockIdx.x;
  const int t = threadIdx.x;
  const int s0 = cbase[cb];
  const int s1 = (cb + 1 < ncb) ? cbase[cb + 1] : E;

  ldeg[t] = 0;
  __syncthreads();
  for (int i = s0 + t; i < s1; i += 256)
    atomicAdd(&ldeg[staging[i].x & 255u], 1);
  __syncthreads();

  const int v = ldeg[t];
  sc[t] = v;
  __syncthreads();
#pragma unroll
  for (int off = 1; off < 256; off <<= 1) {
    const int add = (t >= off) ? sc[t - off] : 0;
    __syncthreads();
    sc[t] += add;
    __syncthreads();
  }
  const int base = s0 + sc[t] - v;
  lcur[t] = base;
  const int dn = (cb << 8) + t;
  if (dn < N) rowptr[dn] = base;
  if (cb == ncb - 1 && t == 0) rowptr[N] = E;
  __syncthreads();

  for (int i = s0 + t; i < s1; i += 256) {
    const uint2 r = staging[i];
    const int pos = atomicAdd(&lcur[r.x & 255u], 1);
    srcet[pos] = (int)r.y;
  }
}

// ================= per-node relation gather =================
__global__ __launch_bounds__(256) void gather_rel(
    const float* __restrict__ h, const int* __restrict__ rowptr,
    const int* __restrict__ srcet, float* __restrict__ aggr, int N,
    int relu_in) {
  const int n = blockIdx.x * 4 + (threadIdx.x >> 6);
  const int lane = threadIdx.x & 63;
  const int g = lane >> 4;    // edge slot 0..3
  const int t = lane & 15;    // float4 chunk 0..15
  if (n >= N) return;
  const int beg = rowptr[n], end = rowptr[n + 1];

  float4 a0 = make_float4(0.f, 0.f, 0.f, 0.f);
  float4 a1 = a0, a2 = a0, a3 = a0;

  for (int j = beg + g; j < end; j += 4) {
    const int se = srcet[j];
    const int s = se >> 2;
    const int r = se & 3;
    float4 v = *(const float4*)(h + ((size_t)s << 6) + (t << 2));
    if (relu_in) {
      v.x = fmaxf(v.x, 0.f); v.y = fmaxf(v.y, 0.f);
      v.z = fmaxf(v.z, 0.f); v.w = fmaxf(v.w, 0.f);
    }
    if (r == 0) { a0.x += v.x; a0.y += v.y; a0.z += v.z; a0.w += v.w; }
    else if (r == 1) { a1.x += v.x; a1.y += v.y; a1.z += v.z; a1.w += v.w; }
    else if (r == 2) { a2.x += v.x; a2.y += v.y; a2.z += v.z; a2.w += v.w; }
    else { a3.x += v.x; a3.y += v.y; a3.z += v.z; a3.w += v.w; }
  }

#pragma unroll
  for (int off = 16; off <= 32; off <<= 1) {
    a0.x += __shfl_xor(a0.x, off); a0.y += __shfl_xor(a0.y, off);
    a0.z += __shfl_xor(a0.z, off); a0.w += __shfl_xor(a0.w, off);
    a1.x += __shfl_xor(a1.x, off); a1.y += __shfl_xor(a1.y, off);
    a1.z += __shfl_xor(a1.z, off); a1.w += __shfl_xor(a1.w, off);
    a2.x += __shfl_xor(a2.x, off); a2.y += __shfl_xor(a2.y, off);
    a2.z += __shfl_xor(a2.z, off); a2.w += __shfl_xor(a2.w, off);
    a3.x += __shfl_xor(a3.x, off); a3.y += __shfl_xor(a3.y, off);
    a3.z += __shfl_xor(a3.z, off); a3.w += __shfl_xor(a3.w, off);
  }

  const float4 res = (g == 0) ? a0 : (g == 1) ? a1 : (g == 2) ? a2 : a3;
  *(float4*)(aggr + ((size_t)n << 8) + (g << 6) + (t << 2)) = res;
}

// ================= dense: hnext = sum_r aggr[r]@Wrel[r] + relu?(h)@Wloop + brel ==========
__global__ __launch_bounds__(256) void rgcn_dense(
    const float* __restrict__ aggr, const float* __restrict__ hin,
    const float* __restrict__ Wrel, const float* __restrict__ Wloop,
    const float* __restrict__ brel, float* __restrict__ hnext, int N,
    int relu_in) {
  const int lane = threadIdx.x & 63;
  const int wv = threadIdx.x >> 6;
  const int c0 = __builtin_amdgcn_readfirstlane(wv << 4);
  const int n = blockIdx.x * 64 + lane;

  float acc[16];
#pragma unroll
  for (int jj = 0; jj < 16; ++jj) acc[jj] = brel[c0 + jj];

  float in[DD];
#pragma unroll 1
  for (int m = 0; m < 5; ++m) {
    const float* __restrict__ W =
        (m < 4) ? (Wrel + (size_t)m * DD * DD) : Wloop;
    if (n < N) {
      const float4* p = (m < 4)
                            ? (const float4*)(aggr + ((size_t)n << 8) + (m << 6))
                            : (const float4*)(hin + ((size_t)n << 6));
#pragma unroll
      for (int t = 0; t < DD / 4; ++t) {
        float4 v = p[t];
        if (m == 4 && relu_in) {
          v.x = fmaxf(v.x, 0.f); v.y = fmaxf(v.y, 0.f);
          v.z = fmaxf(v.z, 0.f); v.w = fmaxf(v.w, 0.f);
        }
        in[4 * t + 0] = v.x; in[4 * t + 1] = v.y;
        in[4 * t + 2] = v.z; in[4 * t + 3] = v.w;
      }
    } else {
#pragma unroll
      for (int t = 0; t < DD; ++t) in[t] = 0.f;
    }
#pragma unroll
    for (int k = 0; k < DD; ++k) {
      const float hk = in[k];
#pragma unroll
      for (int jj = 0; jj < 16; ++jj)
        acc[jj] = fmaf(hk, W[k * DD + c0 + jj], acc[jj]);
    }
  }
  if (n < N) {
    float* o = hnext + ((size_t)n << 6) + c0;
#pragma unroll
    for (int jj = 0; jj < 16; jj += 4)
      *(float4*)(o + jj) =
          make_float4(acc[jj], acc[jj + 1], acc[jj + 2], acc[jj + 3]);
  }
}

// ================= z = relu(h) @ Wg =================
__global__ __launch_bounds__(256) void gemm_relu64(const float* __restrict__ hin,
                                                   const float* __restrict__ W,
                                                   float* __restrict__ out,
                                                   int N) {
  const int lane = threadIdx.x & 63;
  const int wv = threadIdx.x >> 6;
  const int c0 = __builtin_amdgcn_readfirstlane(wv << 4);
  const int n = blockIdx.x * 64 + lane;

  float h[DD];
  if (n < N) {
    const float4* hp = (const float4*)(hin + (size_t)n * DD);
#pragma unroll
    for (int t = 0; t < DD / 4; ++t) {
      float4 v = hp[t];
      v.x = fmaxf(v.x, 0.f); v.y = fmaxf(v.y, 0.f);
      v.z = fmaxf(v.z, 0.f); v.w = fmaxf(v.w, 0.f);
      h[4 * t + 0] = v.x; h[4 * t + 1] = v.y;
      h[4 * t + 2] = v.z; h[4 * t + 3] = v.w;
    }
  } else {
#pragma unroll
    for (int t = 0; t < DD; ++t) h[t] = 0.f;
  }
  float acc[16];
#pragma unroll
  for (int j = 0; j < 16; ++j) acc[j] = 0.f;
#pragma unroll
  for (int k = 0; k < DD; ++k) {
    const float hk = h[k];
#pragma unroll
    for (int j = 0; j < 16; ++j)
      acc[j] = fmaf(hk, W[k * DD + c0 + j], acc[j]);
  }
  if (n < N) {
    float* o = out + ((size_t)n << 6) + c0;
#pragma unroll
    for (int j = 0; j < 16; j += 4)
      *(float4*)(o + j) =
          make_float4(acc[j], acc[j + 1], acc[j + 2], acc[j + 3]);
  }
}

// ================= GAT: el/er per node =================
__global__ __launch_bounds__(256) void el_er_k(
    const float* __restrict__ z, const float* __restrict__ al,
    const float* __restrict__ ar, float* __restrict__ el,
    float* __restrict__ er, int N) {
  int n = blockIdx.x * 4 + (threadIdx.x >> 6);
  int lane = threadIdx.x & 63;
  if (n >= N) return;
  float v = z[(size_t)n * DD + lane];
  float pl = v * al[lane];
  float pr = v * ar[lane];
#pragma unroll
  for (int off = 32; off > 0; off >>= 1) {
    pl += __shfl_down(pl, off);
    pr += __shfl_down(pr, off);
  }
  if (lane == 0) {
    el[n] = pl;
    er[n] = pr;
  }
}

// ================= fused GAT aggregation =================
__global__ __launch_bounds__(256) void gat_fused(
    const float* __restrict__ z, const float* __restrict__ el,
    const float* __restrict__ er, const int* __restrict__ rowptr,
    const int* __restrict__ srcet, float* __restrict__ hg, int N) {
  const int n = blockIdx.x * 4 + (threadIdx.x >> 6);
  const int lane = threadIdx.x & 63;
  const int g = lane >> 4;
  const int t = lane & 15;
  if (n >= N) return;
  const int beg = rowptr[n], end = rowptr[n + 1];
  const float ern = er[n];

  float m = -1e30f, den = 0.f;
  for (int j = beg + lane; j < end; j += 64) {
    const int s = srcet[j] >> 2;
    float x = el[s] + ern;
    x = (x > 0.f) ? x : 0.2f * x;
    if (x > m) {
      den *= __expf(m - x);
      m = x;
    }
    den += __expf(x - m);
  }
#pragma unroll
  for (int off = 1; off < 64; off <<= 1) {
    float mo = __shfl_xor(m, off);
    float dn = __shfl_xor(den, off);
    float M = fmaxf(m, mo);
    den = den * __expf(m - M) + dn * __expf(mo - M);
    m = M;
  }

  float4 num = make_float4(0.f, 0.f, 0.f, 0.f);
  for (int j = beg + g; j < end; j += 4) {
    const int se = srcet[j];
    const int s = se >> 2;
    float x = el[s] + ern;
    x = (x > 0.f) ? x : 0.2f * x;
    const float w = __expf(x - m);
    float4 v = *(const float4*)(z + ((size_t)s << 6) + (t << 2));
    num.x = fmaf(w, v.x, num.x);
    num.y = fmaf(w, v.y, num.y);
    num.z = fmaf(w, v.z, num.z);
    num.w = fmaf(w, v.w, num.w);
  }
#pragma unroll
  for (int off = 16; off <= 32; off <<= 1) {
    num.x += __shfl_xor(num.x, off);
    num.y += __shfl_xor(num.y, off);
    num.z += __shfl_xor(num.z, off);
    num.w += __shfl_xor(num.w, off);
  }
  if (g == 0) {
    const float inv = 1.f / fmaxf(den, 1e-9f);
    float4 o = make_float4(num.x * inv, num.y * inv, num.z * inv, num.w * inv);
    *(float4*)(hg + ((size_t)n << 6) + (t << 2)) = o;
  }
}

// ================= pooled head, two-level =================
__global__ __launch_bounds__(256) void pool_head2(
    const float* __restrict__ hg, const float* __restrict__ Wd,
    const int* __restrict__ gids, float* __restrict__ out, int N, int B) {
  __shared__ float acc[1024];
  for (int i = threadIdx.x; i < B; i += 256) acc[i] = 0.f;
  __syncthreads();

  const int wv = threadIdx.x >> 6;
  const int lane = threadIdx.x & 63;
  const int sub = lane & 3;
  const int idx = lane >> 2;

  const float4 w0 = *(const float4*)(Wd + (sub << 4) + 0);
  const float4 w1 = *(const float4*)(Wd + (sub << 4) + 4);
  const float4 w2 = *(const float4*)(Wd + (sub << 4) + 8);
  const float4 w3 = *(const float4*)(Wd + (sub << 4) + 12);

  const int base0 = blockIdx.x * POOL_NPB;
#pragma unroll 1
  for (int it = 0; it < POOL_NPB / 64; ++it) {
    const int n = base0 + it * 64 + wv * 16 + idx;
    if (n < N) {
      const float* p = hg + ((size_t)n << 6) + (sub << 4);
      const float4 v0 = *(const float4*)(p + 0);
      const float4 v1 = *(const float4*)(p + 4);
      const float4 v2 = *(const float4*)(p + 8);
      const float4 v3 = *(const float4*)(p + 12);
      float s = v0.x * w0.x + v0.y * w0.y + v0.z * w0.z + v0.w * w0.w;
      s = fmaf(v1.x, w1.x, s); s = fmaf(v1.y, w1.y, s);
      s = fmaf(v1.z, w1.z, s); s = fmaf(v1.w, w1.w, s);
      s = fmaf(v2.x, w2.x, s); s = fmaf(v2.y, w2.y, s);
      s = fmaf(v2.z, w2.z, s); s = fmaf(v2.w, w2.w, s);
      s = fmaf(v3.x, w3.x, s); s = fmaf(v3.y, w3.y, s);
      s = fmaf(v3.z, w3.z, s); s = fmaf(v3.w, w3.w, s);
      s += __shfl_xor(s, 1);
      s += __shfl_xor(s, 2);
      if (sub == 0) atomicAdd(&acc[gids[n]], s);
    }
  }
  __syncthreads();
  for (int i = threadIdx.x; i < B; i += 256) {
    const float v = acc[i];
    if (v != 0.f) unsafeAtomicAdd(out + i, v);
  }
}

__global__ void init_out_k(float* out, const float* bd, int n) {
  int i = blockIdx.x * blockDim.x + threadIdx.x;
  if (i < n) out[i] = bd[0];
}

// ================= launch =================
extern "C" void kernel_launch(void* const* d_in, const int* in_sizes, int n_in,
                              void* d_out, int out_size, void* d_ws,
                              size_t ws_size, hipStream_t stream) {
  const float* h0 = (const float*)d_in[0];
  const float* Wrel = (const float*)d_in[1];
  const float* Wloop = (const float*)d_in[2];
  const float* brel = (const float*)d_in[3];
  const float* Wg = (const float*)d_in[4];
  const float* al = (const float*)d_in[5];
  const float* ar = (const float*)d_in[6];
  const float* Wd = (const float*)d_in[7];
  const float* bd = (const float*)d_in[8];
  const int* src = (const int*)d_in[9];
  const int* dst = (const int*)d_in[10];
  const int* et = (const int*)d_in[11];
  const int* gids = (const int*)d_in[12];

  const int N = in_sizes[0] / DD;
  const int E = in_sizes[9];
  const int L = in_sizes[2] / (DD * DD);
  float* out = (float*)d_out;

  // ---- workspace layout ----
  float* wsf = (float*)d_ws;
  float* hA = wsf;                          // N*64
  float* hB = hA + (size_t)N * DD;          // N*64
  float* aggr = hB + (size_t)N * DD;        // N*256
  int* rowptr = (int*)(aggr + (size_t)N * 4 * DD);  // N+1
  int* srcet = rowptr + N + 1;              // E
  float* el = (float*)(srcet + E);          // N
  float* er = el + N;                       // N
  int* chist = (int*)(er + N);              // 256
  int* gcur = chist + 256;                  // 256
  int* cbase = gcur + 256;                  // 256
  uint2* staging = (uint2*)aggr;            // E uint2, overlays aggr
  float* hg = aggr;                         // overlay: aggr dead after last dense

  dim3 b256(256);
  const int grid_dense = (N + 63) / 64;
  const int grid_n4 = (N + 3) / 4;
  const int nfb = (E + EPB - 1) / EPB;
  const int ncb = (N + 255) >> 8;

  hipLaunchKernelGGL(init_out_k, dim3((out_size + 255) / 256), b256, 0, stream,
                     out, bd, out_size);

  // ---- CSR build (hierarchical fill, no global deg pass) ----
  hipMemsetAsync(chist, 0, 256 * 4, stream);
  hipLaunchKernelGGL(k_hist, dim3(nfb), b256, 0, stream, dst, chist, E);
  hipLaunchKernelGGL(cscan, dim3(1), b256, 0, stream, chist, gcur, cbase);
  hipLaunchKernelGGL(f2_coarse, dim3(nfb), b256, 0, stream, src, dst, et, gcur,
                     staging, E);
  hipLaunchKernelGGL(f3_fine2, dim3(ncb), b256, 0, stream, staging, cbase,
                     rowptr, srcet, N, E, ncb);

  // ---- RGCN layers ----
  const float* cur = h0;
  float* nxt = hA;
  for (int l = 0; l < L; ++l) {
    hipLaunchKernelGGL(gather_rel, dim3(grid_n4), b256, 0, stream, cur, rowptr,
                       srcet, aggr, N, l > 0 ? 1 : 0);
    hipLaunchKernelGGL(rgcn_dense, dim3(grid_dense), b256, 0, stream, aggr, cur,
                       Wrel + (size_t)l * 4 * DD * DD,
                       Wloop + (size_t)l * DD * DD, brel + (size_t)l * DD, nxt,
                       N, l > 0 ? 1 : 0);
    cur = nxt;
    nxt = (cur == hA) ? hB : hA;
  }

  // ---- GAT ----
  float* zb = nxt;
  hipLaunchKernelGGL(gemm_relu64, dim3(grid_dense), b256, 0, stream, cur, Wg,
                     zb, N);
  hipLaunchKernelGGL(el_er_k, dim3(grid_n4), b256, 0, stream, zb, al, ar, el,
                     er, N);
  hipLaunchKernelGGL(gat_fused, dim3(grid_n4), b256, 0, stream, zb, el, er,
                     rowptr, srcet, hg, N);

  const int grid_pool = (N + POOL_NPB - 1) / POOL_NPB;
  hipLaunchKernelGGL(pool_head2, dim3(grid_pool), b256, 0, stream, hg, Wd, gids,
                     out, N, out_size);
}

// Round 9
// 740.277 us; speedup vs baseline: 1.2436x; 1.0160x over previous
//
#include <hip/hip_runtime.h>

#define DD 64
#define POOL_NPB 512
#define EPB 1024  // edges per block in fill pipeline

// ================= coarse histogram (LDS only) =================
__global__ __launch_bounds__(256) void k_hist(const int* __restrict__ dst,
                                              int* __restrict__ chist, int E) {
  __shared__ int lh[256];
  lh[threadIdx.x] = 0;
  __syncthreads();
  const int base = blockIdx.x * EPB;
#pragma unroll
  for (int k = 0; k < EPB / 256; ++k) {
    const int e = base + k * 256 + threadIdx.x;
    if (e < E) atomicAdd(&lh[dst[e] >> 8], 1);
  }
  __syncthreads();
  const int v = lh[threadIdx.x];
  if (v) atomicAdd(&chist[threadIdx.x], v);
}

// ---- scan of coarse histogram -> gcur (mutable) + cbase (stable) ----
__global__ __launch_bounds__(256) void cscan(const int* __restrict__ chist,
                                             int* __restrict__ gcur,
                                             int* __restrict__ cbase) {
  __shared__ int s[256];
  const int t = threadIdx.x;
  const int v = chist[t];
  s[t] = v;
  __syncthreads();
#pragma unroll
  for (int off = 1; off < 256; off <<= 1) {
    const int add = (t >= off) ? s[t - off] : 0;
    __syncthreads();
    s[t] += add;
    __syncthreads();
  }
  const int ex = s[t] - v;
  gcur[t] = ex;
  cbase[t] = ex;
}

// ---- coarse scatter: LDS-reordered, bucket-contiguous 4B packed records ----
// record = (d & 255) << 24 | se   (se = (src<<2)|et < 2^18)
__global__ __launch_bounds__(256) void f2_coarse(
    const int* __restrict__ src, const int* __restrict__ dst,
    const int* __restrict__ et, int* __restrict__ gcur,
    unsigned* __restrict__ staging, int E) {
  __shared__ int lcnt[256];
  __shared__ int sc[256];
  __shared__ int lbase[256];
  __shared__ int gb[256];
  __shared__ unsigned rec[EPB];
  __shared__ unsigned char rbk[EPB];

  const int t = threadIdx.x;
  const int base = blockIdx.x * EPB;
  const int bc = min(EPB, E - base);

  lcnt[t] = 0;
  __syncthreads();

  int d_[EPB / 256], se_[EPB / 256], rk_[EPB / 256];
#pragma unroll
  for (int k = 0; k < EPB / 256; ++k) {
    const int e = base + k * 256 + t;
    if (e < E) {
      const int d = dst[e];
      d_[k] = d;
      se_[k] = (src[e] << 2) | et[e];
      rk_[k] = atomicAdd(&lcnt[d >> 8], 1);
    } else {
      d_[k] = -1;
    }
  }
  __syncthreads();

  // exclusive scan lcnt -> lbase
  const int lv = lcnt[t];
  sc[t] = lv;
  __syncthreads();
#pragma unroll
  for (int off = 1; off < 256; off <<= 1) {
    const int add = (t >= off) ? sc[t - off] : 0;
    __syncthreads();
    sc[t] += add;
    __syncthreads();
  }
  lbase[t] = sc[t] - lv;
  gb[t] = lv ? atomicAdd(&gcur[t], lv) : 0;
  __syncthreads();

#pragma unroll
  for (int k = 0; k < EPB / 256; ++k) {
    if (d_[k] >= 0) {
      const int cb = d_[k] >> 8;
      const int pos = lbase[cb] + rk_[k];
      rec[pos] = ((unsigned)(d_[k] & 255) << 24) | (unsigned)se_[k];
      rbk[pos] = (unsigned char)cb;
    }
  }
  __syncthreads();

  for (int idx = t; idx < bc; idx += 256) {
    const int cb = rbk[idx];
    staging[gb[cb] + (idx - lbase[cb])] = rec[idx];
  }
}

// ---- fine placement: one (1024-thread) block per coarse bucket.
//      rowptr[d] = cbase[cb] + exclusive_scan(local deg). ----
__global__ __launch_bounds__(1024) void f3_fine2(
    const unsigned* __restrict__ staging, const int* __restrict__ cbase,
    int* __restrict__ rowptr, int* __restrict__ srcet, int N, int E, int ncb) {
  __shared__ int ldeg[256];
  __shared__ int sc[256];
  __shared__ int lcur[256];
  const int cb = blockIdx.x;
  const int t = threadIdx.x;
  const int s0 = cbase[cb];
  const int s1 = (cb + 1 < ncb) ? cbase[cb + 1] : E;

  if (t < 256) ldeg[t] = 0;
  __syncthreads();
  for (int i = s0 + t; i < s1; i += 1024)
    atomicAdd(&ldeg[staging[i] >> 24], 1);
  __syncthreads();

  int v = 0;
  if (t < 256) {
    v = ldeg[t];
    sc[t] = v;
  }
  __syncthreads();
#pragma unroll
  for (int off = 1; off < 256; off <<= 1) {
    int add = 0;
    if (t < 256 && t >= off) add = sc[t - off];
    __syncthreads();
    if (t < 256) sc[t] += add;
    __syncthreads();
  }
  if (t < 256) {
    const int base = s0 + sc[t] - v;
    lcur[t] = base;
    const int dn = (cb << 8) + t;
    if (dn < N) rowptr[dn] = base;
  }
  if (cb == ncb - 1 && t == 0) rowptr[N] = E;
  __syncthreads();

  for (int i = s0 + t; i < s1; i += 1024) {
    const unsigned r = staging[i];
    const int pos = atomicAdd(&lcur[r >> 24], 1);
    srcet[pos] = (int)(r & 0xFFFFFFu);
  }
}

// ================= per-node relation gather =================
__global__ __launch_bounds__(256) void gather_rel(
    const float* __restrict__ h, const int* __restrict__ rowptr,
    const int* __restrict__ srcet, float* __restrict__ aggr, int N,
    int relu_in) {
  const int n = blockIdx.x * 4 + (threadIdx.x >> 6);
  const int lane = threadIdx.x & 63;
  const int g = lane >> 4;    // edge slot 0..3
  const int t = lane & 15;    // float4 chunk 0..15
  if (n >= N) return;
  const int beg = rowptr[n], end = rowptr[n + 1];

  float4 a0 = make_float4(0.f, 0.f, 0.f, 0.f);
  float4 a1 = a0, a2 = a0, a3 = a0;

  for (int j = beg + g; j < end; j += 4) {
    const int se = srcet[j];
    const int s = se >> 2;
    const int r = se & 3;
    float4 v = *(const float4*)(h + ((size_t)s << 6) + (t << 2));
    if (relu_in) {
      v.x = fmaxf(v.x, 0.f); v.y = fmaxf(v.y, 0.f);
      v.z = fmaxf(v.z, 0.f); v.w = fmaxf(v.w, 0.f);
    }
    if (r == 0) { a0.x += v.x; a0.y += v.y; a0.z += v.z; a0.w += v.w; }
    else if (r == 1) { a1.x += v.x; a1.y += v.y; a1.z += v.z; a1.w += v.w; }
    else if (r == 2) { a2.x += v.x; a2.y += v.y; a2.z += v.z; a2.w += v.w; }
    else { a3.x += v.x; a3.y += v.y; a3.z += v.z; a3.w += v.w; }
  }

#pragma unroll
  for (int off = 16; off <= 32; off <<= 1) {
    a0.x += __shfl_xor(a0.x, off); a0.y += __shfl_xor(a0.y, off);
    a0.z += __shfl_xor(a0.z, off); a0.w += __shfl_xor(a0.w, off);
    a1.x += __shfl_xor(a1.x, off); a1.y += __shfl_xor(a1.y, off);
    a1.z += __shfl_xor(a1.z, off); a1.w += __shfl_xor(a1.w, off);
    a2.x += __shfl_xor(a2.x, off); a2.y += __shfl_xor(a2.y, off);
    a2.z += __shfl_xor(a2.z, off); a2.w += __shfl_xor(a2.w, off);
    a3.x += __shfl_xor(a3.x, off); a3.y += __shfl_xor(a3.y, off);
    a3.z += __shfl_xor(a3.z, off); a3.w += __shfl_xor(a3.w, off);
  }

  const float4 res = (g == 0) ? a0 : (g == 1) ? a1 : (g == 2) ? a2 : a3;
  *(float4*)(aggr + ((size_t)n << 8) + (g << 6) + (t << 2)) = res;
}

// ================= dense: hnext = sum_r aggr[r]@Wrel[r] + relu?(h)@Wloop + brel ==========
__global__ __launch_bounds__(256) void rgcn_dense(
    const float* __restrict__ aggr, const float* __restrict__ hin,
    const float* __restrict__ Wrel, const float* __restrict__ Wloop,
    const float* __restrict__ brel, float* __restrict__ hnext, int N,
    int relu_in) {
  const int lane = threadIdx.x & 63;
  const int wv = threadIdx.x >> 6;
  const int c0 = __builtin_amdgcn_readfirstlane(wv << 4);
  const int n = blockIdx.x * 64 + lane;

  float acc[16];
#pragma unroll
  for (int jj = 0; jj < 16; ++jj) acc[jj] = brel[c0 + jj];

  float in[DD];
#pragma unroll 1
  for (int m = 0; m < 5; ++m) {
    const float* __restrict__ W =
        (m < 4) ? (Wrel + (size_t)m * DD * DD) : Wloop;
    if (n < N) {
      const float4* p = (m < 4)
                            ? (const float4*)(aggr + ((size_t)n << 8) + (m << 6))
                            : (const float4*)(hin + ((size_t)n << 6));
#pragma unroll
      for (int t = 0; t < DD / 4; ++t) {
        float4 v = p[t];
        if (m == 4 && relu_in) {
          v.x = fmaxf(v.x, 0.f); v.y = fmaxf(v.y, 0.f);
          v.z = fmaxf(v.z, 0.f); v.w = fmaxf(v.w, 0.f);
        }
        in[4 * t + 0] = v.x; in[4 * t + 1] = v.y;
        in[4 * t + 2] = v.z; in[4 * t + 3] = v.w;
      }
    } else {
#pragma unroll
      for (int t = 0; t < DD; ++t) in[t] = 0.f;
    }
#pragma unroll
    for (int k = 0; k < DD; ++k) {
      const float hk = in[k];
#pragma unroll
      for (int jj = 0; jj < 16; ++jj)
        acc[jj] = fmaf(hk, W[k * DD + c0 + jj], acc[jj]);
    }
  }
  if (n < N) {
    float* o = hnext + ((size_t)n << 6) + c0;
#pragma unroll
    for (int jj = 0; jj < 16; jj += 4)
      *(float4*)(o + jj) =
          make_float4(acc[jj], acc[jj + 1], acc[jj + 2], acc[jj + 3]);
  }
}

// ================= z = relu(h) @ Wg =================
__global__ __launch_bounds__(256) void gemm_relu64(const float* __restrict__ hin,
                                                   const float* __restrict__ W,
                                                   float* __restrict__ out,
                                                   int N) {
  const int lane = threadIdx.x & 63;
  const int wv = threadIdx.x >> 6;
  const int c0 = __builtin_amdgcn_readfirstlane(wv << 4);
  const int n = blockIdx.x * 64 + lane;

  float h[DD];
  if (n < N) {
    const float4* hp = (const float4*)(hin + (size_t)n * DD);
#pragma unroll
    for (int t = 0; t < DD / 4; ++t) {
      float4 v = hp[t];
      v.x = fmaxf(v.x, 0.f); v.y = fmaxf(v.y, 0.f);
      v.z = fmaxf(v.z, 0.f); v.w = fmaxf(v.w, 0.f);
      h[4 * t + 0] = v.x; h[4 * t + 1] = v.y;
      h[4 * t + 2] = v.z; h[4 * t + 3] = v.w;
    }
  } else {
#pragma unroll
    for (int t = 0; t < DD; ++t) h[t] = 0.f;
  }
  float acc[16];
#pragma unroll
  for (int j = 0; j < 16; ++j) acc[j] = 0.f;
#pragma unroll
  for (int k = 0; k < DD; ++k) {
    const float hk = h[k];
#pragma unroll
    for (int j = 0; j < 16; ++j)
      acc[j] = fmaf(hk, W[k * DD + c0 + j], acc[j]);
  }
  if (n < N) {
    float* o = out + ((size_t)n << 6) + c0;
#pragma unroll
    for (int j = 0; j < 16; j += 4)
      *(float4*)(o + j) =
          make_float4(acc[j], acc[j + 1], acc[j + 2], acc[j + 3]);
  }
}

// ================= GAT: el/er per node =================
__global__ __launch_bounds__(256) void el_er_k(
    const float* __restrict__ z, const float* __restrict__ al,
    const float* __restrict__ ar, float* __restrict__ el,
    float* __restrict__ er, int N) {
  int n = blockIdx.x * 4 + (threadIdx.x >> 6);
  int lane = threadIdx.x & 63;
  if (n >= N) return;
  float v = z[(size_t)n * DD + lane];
  float pl = v * al[lane];
  float pr = v * ar[lane];
#pragma unroll
  for (int off = 32; off > 0; off >>= 1) {
    pl += __shfl_down(pl, off);
    pr += __shfl_down(pr, off);
  }
  if (lane == 0) {
    el[n] = pl;
    er[n] = pr;
  }
}

// ================= fused GAT aggregation =================
__global__ __launch_bounds__(256) void gat_fused(
    const float* __restrict__ z, const float* __restrict__ el,
    const float* __restrict__ er, const int* __restrict__ rowptr,
    const int* __restrict__ srcet, float* __restrict__ hg, int N) {
  const int n = blockIdx.x * 4 + (threadIdx.x >> 6);
  const int lane = threadIdx.x & 63;
  const int g = lane >> 4;
  const int t = lane & 15;
  if (n >= N) return;
  const int beg = rowptr[n], end = rowptr[n + 1];
  const float ern = er[n];

  float m = -1e30f, den = 0.f;
  for (int j = beg + lane; j < end; j += 64) {
    const int s = srcet[j] >> 2;
    float x = el[s] + ern;
    x = (x > 0.f) ? x : 0.2f * x;
    if (x > m) {
      den *= __expf(m - x);
      m = x;
    }
    den += __expf(x - m);
  }
#pragma unroll
  for (int off = 1; off < 64; off <<= 1) {
    float mo = __shfl_xor(m, off);
    float dn = __shfl_xor(den, off);
    float M = fmaxf(m, mo);
    den = den * __expf(m - M) + dn * __expf(mo - M);
    m = M;
  }

  float4 num = make_float4(0.f, 0.f, 0.f, 0.f);
  for (int j = beg + g; j < end; j += 4) {
    const int se = srcet[j];
    const int s = se >> 2;
    float x = el[s] + ern;
    x = (x > 0.f) ? x : 0.2f * x;
    const float w = __expf(x - m);
    float4 v = *(const float4*)(z + ((size_t)s << 6) + (t << 2));
    num.x = fmaf(w, v.x, num.x);
    num.y = fmaf(w, v.y, num.y);
    num.z = fmaf(w, v.z, num.z);
    num.w = fmaf(w, v.w, num.w);
  }
#pragma unroll
  for (int off = 16; off <= 32; off <<= 1) {
    num.x += __shfl_xor(num.x, off);
    num.y += __shfl_xor(num.y, off);
    num.z += __shfl_xor(num.z, off);
    num.w += __shfl_xor(num.w, off);
  }
  if (g == 0) {
    const float inv = 1.f / fmaxf(den, 1e-9f);
    float4 o = make_float4(num.x * inv, num.y * inv, num.z * inv, num.w * inv);
    *(float4*)(hg + ((size_t)n << 6) + (t << 2)) = o;
  }
}

// ================= pooled head, two-level =================
__global__ __launch_bounds__(256) void pool_head2(
    const float* __restrict__ hg, const float* __restrict__ Wd,
    const int* __restrict__ gids, float* __restrict__ out, int N, int B) {
  __shared__ float acc[1024];
  for (int i = threadIdx.x; i < B; i += 256) acc[i] = 0.f;
  __syncthreads();

  const int wv = threadIdx.x >> 6;
  const int lane = threadIdx.x & 63;
  const int sub = lane & 3;
  const int idx = lane >> 2;

  const float4 w0 = *(const float4*)(Wd + (sub << 4) + 0);
  const float4 w1 = *(const float4*)(Wd + (sub << 4) + 4);
  const float4 w2 = *(const float4*)(Wd + (sub << 4) + 8);
  const float4 w3 = *(const float4*)(Wd + (sub << 4) + 12);

  const int base0 = blockIdx.x * POOL_NPB;
#pragma unroll 1
  for (int it = 0; it < POOL_NPB / 64; ++it) {
    const int n = base0 + it * 64 + wv * 16 + idx;
    if (n < N) {
      const float* p = hg + ((size_t)n << 6) + (sub << 4);
      const float4 v0 = *(const float4*)(p + 0);
      const float4 v1 = *(const float4*)(p + 4);
      const float4 v2 = *(const float4*)(p + 8);
      const float4 v3 = *(const float4*)(p + 12);
      float s = v0.x * w0.x + v0.y * w0.y + v0.z * w0.z + v0.w * w0.w;
      s = fmaf(v1.x, w1.x, s); s = fmaf(v1.y, w1.y, s);
      s = fmaf(v1.z, w1.z, s); s = fmaf(v1.w, w1.w, s);
      s = fmaf(v2.x, w2.x, s); s = fmaf(v2.y, w2.y, s);
      s = fmaf(v2.z, w2.z, s); s = fmaf(v2.w, w2.w, s);
      s = fmaf(v3.x, w3.x, s); s = fmaf(v3.y, w3.y, s);
      s = fmaf(v3.z, w3.z, s); s = fmaf(v3.w, w3.w, s);
      s += __shfl_xor(s, 1);
      s += __shfl_xor(s, 2);
      if (sub == 0) atomicAdd(&acc[gids[n]], s);
    }
  }
  __syncthreads();
  for (int i = threadIdx.x; i < B; i += 256) {
    const float v = acc[i];
    if (v != 0.f) unsafeAtomicAdd(out + i, v);
  }
}

__global__ void init_out_k(float* out, const float* bd, int n) {
  int i = blockIdx.x * blockDim.x + threadIdx.x;
  if (i < n) out[i] = bd[0];
}

// ================= launch =================
extern "C" void kernel_launch(void* const* d_in, const int* in_sizes, int n_in,
                              void* d_out, int out_size, void* d_ws,
                              size_t ws_size, hipStream_t stream) {
  const float* h0 = (const float*)d_in[0];
  const float* Wrel = (const float*)d_in[1];
  const float* Wloop = (const float*)d_in[2];
  const float* brel = (const float*)d_in[3];
  const float* Wg = (const float*)d_in[4];
  const float* al = (const float*)d_in[5];
  const float* ar = (const float*)d_in[6];
  const float* Wd = (const float*)d_in[7];
  const float* bd = (const float*)d_in[8];
  const int* src = (const int*)d_in[9];
  const int* dst = (const int*)d_in[10];
  const int* et = (const int*)d_in[11];
  const int* gids = (const int*)d_in[12];

  const int N = in_sizes[0] / DD;
  const int E = in_sizes[9];
  const int L = in_sizes[2] / (DD * DD);
  float* out = (float*)d_out;

  // ---- workspace layout ----
  float* wsf = (float*)d_ws;
  float* hA = wsf;                          // N*64
  float* hB = hA + (size_t)N * DD;          // N*64
  float* aggr = hB + (size_t)N * DD;        // N*256
  int* rowptr = (int*)(aggr + (size_t)N * 4 * DD);  // N+1
  int* srcet = rowptr + N + 1;              // E
  float* el = (float*)(srcet + E);          // N
  float* er = el + N;                       // N
  int* chist = (int*)(er + N);              // 256
  int* gcur = chist + 256;                  // 256
  int* cbase = gcur + 256;                  // 256
  unsigned* staging = (unsigned*)aggr;      // E uint, overlays aggr
  float* hg = aggr;                         // overlay: aggr dead after last dense

  dim3 b256(256);
  const int grid_dense = (N + 63) / 64;
  const int grid_n4 = (N + 3) / 4;
  const int nfb = (E + EPB - 1) / EPB;
  const int ncb = (N + 255) >> 8;

  hipLaunchKernelGGL(init_out_k, dim3((out_size + 255) / 256), b256, 0, stream,
                     out, bd, out_size);

  // ---- CSR build (hierarchical fill) ----
  hipMemsetAsync(chist, 0, 256 * 4, stream);
  hipLaunchKernelGGL(k_hist, dim3(nfb), b256, 0, stream, dst, chist, E);
  hipLaunchKernelGGL(cscan, dim3(1), b256, 0, stream, chist, gcur, cbase);
  hipLaunchKernelGGL(f2_coarse, dim3(nfb), b256, 0, stream, src, dst, et, gcur,
                     staging, E);
  hipLaunchKernelGGL(f3_fine2, dim3(ncb), dim3(1024), 0, stream, staging, cbase,
                     rowptr, srcet, N, E, ncb);

  // ---- RGCN layers ----
  const float* cur = h0;
  float* nxt = hA;
  for (int l = 0; l < L; ++l) {
    hipLaunchKernelGGL(gather_rel, dim3(grid_n4), b256, 0, stream, cur, rowptr,
                       srcet, aggr, N, l > 0 ? 1 : 0);
    hipLaunchKernelGGL(rgcn_dense, dim3(grid_dense), b256, 0, stream, aggr, cur,
                       Wrel + (size_t)l * 4 * DD * DD,
                       Wloop + (size_t)l * DD * DD, brel + (size_t)l * DD, nxt,
                       N, l > 0 ? 1 : 0);
    cur = nxt;
    nxt = (cur == hA) ? hB : hA;
  }

  // ---- GAT ----
  float* zb = nxt;
  hipLaunchKernelGGL(gemm_relu64, dim3(grid_dense), b256, 0, stream, cur, Wg,
                     zb, N);
  hipLaunchKernelGGL(el_er_k, dim3(grid_n4), b256, 0, stream, zb, al, ar, el,
                     er, N);
  hipLaunchKernelGGL(gat_fused, dim3(grid_n4), b256, 0, stream, zb, el, er,
                     rowptr, srcet, hg, N);

  const int grid_pool = (N + POOL_NPB - 1) / POOL_NPB;
  hipLaunchKernelGGL(pool_head2, dim3(grid_pool), b256, 0, stream, hg, Wd, gids,
                     out, N, out_size);
}

// Round 10
// 702.860 us; speedup vs baseline: 1.3098x; 1.0532x over previous
//
#include <hip/hip_runtime.h>

#define DD 64
#define POOL_NPB 512
#define EPB 1024  // edges per block in fill pipeline

// ================= coarse histogram (LDS only) =================
__global__ __launch_bounds__(256) void k_hist(const int* __restrict__ dst,
                                              int* __restrict__ chist, int E) {
  __shared__ int lh[256];
  lh[threadIdx.x] = 0;
  __syncthreads();
  const int base = blockIdx.x * EPB;
#pragma unroll
  for (int k = 0; k < EPB / 256; ++k) {
    const int e = base + k * 256 + threadIdx.x;
    if (e < E) atomicAdd(&lh[dst[e] >> 8], 1);
  }
  __syncthreads();
  const int v = lh[threadIdx.x];
  if (v) atomicAdd(&chist[threadIdx.x], v);
}

// ---- scan of coarse histogram -> gcur (mutable) + cbase (stable) ----
__global__ __launch_bounds__(256) void cscan(const int* __restrict__ chist,
                                             int* __restrict__ gcur,
                                             int* __restrict__ cbase) {
  __shared__ int s[256];
  const int t = threadIdx.x;
  const int v = chist[t];
  s[t] = v;
  __syncthreads();
#pragma unroll
  for (int off = 1; off < 256; off <<= 1) {
    const int add = (t >= off) ? s[t - off] : 0;
    __syncthreads();
    s[t] += add;
    __syncthreads();
  }
  const int ex = s[t] - v;
  gcur[t] = ex;
  cbase[t] = ex;
}

// ---- coarse scatter: LDS-reordered, bucket-contiguous 4B packed records ----
// record = (d & 255) << 24 | se   (se = (src<<2)|et < 2^18)
__global__ __launch_bounds__(256) void f2_coarse(
    const int* __restrict__ src, const int* __restrict__ dst,
    const int* __restrict__ et, int* __restrict__ gcur,
    unsigned* __restrict__ staging, int E) {
  __shared__ int lcnt[256];
  __shared__ int sc[256];
  __shared__ int lbase[256];
  __shared__ int gb[256];
  __shared__ unsigned rec[EPB];
  __shared__ unsigned char rbk[EPB];

  const int t = threadIdx.x;
  const int base = blockIdx.x * EPB;
  const int bc = min(EPB, E - base);

  lcnt[t] = 0;
  __syncthreads();

  int d_[EPB / 256], se_[EPB / 256], rk_[EPB / 256];
#pragma unroll
  for (int k = 0; k < EPB / 256; ++k) {
    const int e = base + k * 256 + t;
    if (e < E) {
      const int d = dst[e];
      d_[k] = d;
      se_[k] = (src[e] << 2) | et[e];
      rk_[k] = atomicAdd(&lcnt[d >> 8], 1);
    } else {
      d_[k] = -1;
    }
  }
  __syncthreads();

  // exclusive scan lcnt -> lbase
  const int lv = lcnt[t];
  sc[t] = lv;
  __syncthreads();
#pragma unroll
  for (int off = 1; off < 256; off <<= 1) {
    const int add = (t >= off) ? sc[t - off] : 0;
    __syncthreads();
    sc[t] += add;
    __syncthreads();
  }
  lbase[t] = sc[t] - lv;
  gb[t] = lv ? atomicAdd(&gcur[t], lv) : 0;
  __syncthreads();

#pragma unroll
  for (int k = 0; k < EPB / 256; ++k) {
    if (d_[k] >= 0) {
      const int cb = d_[k] >> 8;
      const int pos = lbase[cb] + rk_[k];
      rec[pos] = ((unsigned)(d_[k] & 255) << 24) | (unsigned)se_[k];
      rbk[pos] = (unsigned char)cb;
    }
  }
  __syncthreads();

  for (int idx = t; idx < bc; idx += 256) {
    const int cb = rbk[idx];
    staging[gb[cb] + (idx - lbase[cb])] = rec[idx];
  }
}

// ---- fine placement, 1024 bins = (d&255)*4 + rel: emits edges sorted by
//      (dst, rel) so the gather's relation branch is wave-uniform. ----
__global__ __launch_bounds__(1024) void f3_fine3(
    const unsigned* __restrict__ staging, const int* __restrict__ cbase,
    int* __restrict__ rowptr, int* __restrict__ srcet, int N, int E, int ncb) {
  __shared__ int ldeg[1024];
  __shared__ int sc[1024];
  __shared__ int lcur[1024];
  const int cb = blockIdx.x;
  const int t = threadIdx.x;
  const int s0 = cbase[cb];
  const int s1 = (cb + 1 < ncb) ? cbase[cb + 1] : E;

  ldeg[t] = 0;
  __syncthreads();
  for (int i = s0 + t; i < s1; i += 1024) {
    const unsigned r = staging[i];
    atomicAdd(&ldeg[((r >> 24) << 2) | (r & 3u)], 1);
  }
  __syncthreads();

  const int v = ldeg[t];
  sc[t] = v;
  __syncthreads();
#pragma unroll
  for (int off = 1; off < 1024; off <<= 1) {
    const int add = (t >= off) ? sc[t - off] : 0;
    __syncthreads();
    sc[t] += add;
    __syncthreads();
  }
  const int base = s0 + sc[t] - v;
  lcur[t] = base;
  if ((t & 3) == 0) {
    const int dn = (cb << 8) + (t >> 2);
    if (dn < N) rowptr[dn] = base;
  }
  if (cb == ncb - 1 && t == 0) rowptr[N] = E;
  __syncthreads();

  for (int i = s0 + t; i < s1; i += 1024) {
    const unsigned r = staging[i];
    const int pos = atomicAdd(&lcur[((r >> 24) << 2) | (r & 3u)], 1);
    srcet[pos] = (int)(r & 0xFFFFFFu);
  }
}

// ================= per-node relation gather (edges (dst,rel)-sorted) ==========
__global__ __launch_bounds__(256) void gather_rel(
    const float* __restrict__ h, const int* __restrict__ rowptr,
    const int* __restrict__ srcet, float* __restrict__ aggr, int N,
    int relu_in) {
  const int n = blockIdx.x * 4 + (threadIdx.x >> 6);
  const int lane = threadIdx.x & 63;
  const int g = lane >> 4;    // edge slot 0..3
  const int t = lane & 15;    // float4 chunk 0..15
  if (n >= N) return;
  const int beg = rowptr[n], end = rowptr[n + 1];

  float4 a0 = make_float4(0.f, 0.f, 0.f, 0.f);
  float4 a1 = a0, a2 = a0, a3 = a0;

  int j = beg + g;
  for (; j + 4 < end; j += 8) {
    const int se0 = srcet[j];
    const int se1 = srcet[j + 4];
    float4 v0 = *(const float4*)(h + ((size_t)(se0 >> 2) << 6) + (t << 2));
    float4 v1 = *(const float4*)(h + ((size_t)(se1 >> 2) << 6) + (t << 2));
    if (relu_in) {
      v0.x = fmaxf(v0.x, 0.f); v0.y = fmaxf(v0.y, 0.f);
      v0.z = fmaxf(v0.z, 0.f); v0.w = fmaxf(v0.w, 0.f);
      v1.x = fmaxf(v1.x, 0.f); v1.y = fmaxf(v1.y, 0.f);
      v1.z = fmaxf(v1.z, 0.f); v1.w = fmaxf(v1.w, 0.f);
    }
    const int r0 = se0 & 3;
    if (r0 == 0) { a0.x += v0.x; a0.y += v0.y; a0.z += v0.z; a0.w += v0.w; }
    else if (r0 == 1) { a1.x += v0.x; a1.y += v0.y; a1.z += v0.z; a1.w += v0.w; }
    else if (r0 == 2) { a2.x += v0.x; a2.y += v0.y; a2.z += v0.z; a2.w += v0.w; }
    else { a3.x += v0.x; a3.y += v0.y; a3.z += v0.z; a3.w += v0.w; }
    const int r1 = se1 & 3;
    if (r1 == 0) { a0.x += v1.x; a0.y += v1.y; a0.z += v1.z; a0.w += v1.w; }
    else if (r1 == 1) { a1.x += v1.x; a1.y += v1.y; a1.z += v1.z; a1.w += v1.w; }
    else if (r1 == 2) { a2.x += v1.x; a2.y += v1.y; a2.z += v1.z; a2.w += v1.w; }
    else { a3.x += v1.x; a3.y += v1.y; a3.z += v1.z; a3.w += v1.w; }
  }
  if (j < end) {
    const int se0 = srcet[j];
    float4 v0 = *(const float4*)(h + ((size_t)(se0 >> 2) << 6) + (t << 2));
    if (relu_in) {
      v0.x = fmaxf(v0.x, 0.f); v0.y = fmaxf(v0.y, 0.f);
      v0.z = fmaxf(v0.z, 0.f); v0.w = fmaxf(v0.w, 0.f);
    }
    const int r0 = se0 & 3;
    if (r0 == 0) { a0.x += v0.x; a0.y += v0.y; a0.z += v0.z; a0.w += v0.w; }
    else if (r0 == 1) { a1.x += v0.x; a1.y += v0.y; a1.z += v0.z; a1.w += v0.w; }
    else if (r0 == 2) { a2.x += v0.x; a2.y += v0.y; a2.z += v0.z; a2.w += v0.w; }
    else { a3.x += v0.x; a3.y += v0.y; a3.z += v0.z; a3.w += v0.w; }
  }

#pragma unroll
  for (int off = 16; off <= 32; off <<= 1) {
    a0.x += __shfl_xor(a0.x, off); a0.y += __shfl_xor(a0.y, off);
    a0.z += __shfl_xor(a0.z, off); a0.w += __shfl_xor(a0.w, off);
    a1.x += __shfl_xor(a1.x, off); a1.y += __shfl_xor(a1.y, off);
    a1.z += __shfl_xor(a1.z, off); a1.w += __shfl_xor(a1.w, off);
    a2.x += __shfl_xor(a2.x, off); a2.y += __shfl_xor(a2.y, off);
    a2.z += __shfl_xor(a2.z, off); a2.w += __shfl_xor(a2.w, off);
    a3.x += __shfl_xor(a3.x, off); a3.y += __shfl_xor(a3.y, off);
    a3.z += __shfl_xor(a3.z, off); a3.w += __shfl_xor(a3.w, off);
  }

  const float4 res = (g == 0) ? a0 : (g == 1) ? a1 : (g == 2) ? a2 : a3;
  *(float4*)(aggr + ((size_t)n << 8) + (g << 6) + (t << 2)) = res;
}

// ================= dense: hnext = sum_r aggr[r]@Wrel[r] + relu?(h)@Wloop + brel ==========
__global__ __launch_bounds__(256) void rgcn_dense(
    const float* __restrict__ aggr, const float* __restrict__ hin,
    const float* __restrict__ Wrel, const float* __restrict__ Wloop,
    const float* __restrict__ brel, float* __restrict__ hnext, int N,
    int relu_in) {
  const int lane = threadIdx.x & 63;
  const int wv = threadIdx.x >> 6;
  const int c0 = __builtin_amdgcn_readfirstlane(wv << 4);
  const int n = blockIdx.x * 64 + lane;

  float acc[16];
#pragma unroll
  for (int jj = 0; jj < 16; ++jj) acc[jj] = brel[c0 + jj];

  float in[DD];
#pragma unroll 1
  for (int m = 0; m < 5; ++m) {
    const float* __restrict__ W =
        (m < 4) ? (Wrel + (size_t)m * DD * DD) : Wloop;
    if (n < N) {
      const float4* p = (m < 4)
                            ? (const float4*)(aggr + ((size_t)n << 8) + (m << 6))
                            : (const float4*)(hin + ((size_t)n << 6));
#pragma unroll
      for (int t = 0; t < DD / 4; ++t) {
        float4 v = p[t];
        if (m == 4 && relu_in) {
          v.x = fmaxf(v.x, 0.f); v.y = fmaxf(v.y, 0.f);
          v.z = fmaxf(v.z, 0.f); v.w = fmaxf(v.w, 0.f);
        }
        in[4 * t + 0] = v.x; in[4 * t + 1] = v.y;
        in[4 * t + 2] = v.z; in[4 * t + 3] = v.w;
      }
    } else {
#pragma unroll
      for (int t = 0; t < DD; ++t) in[t] = 0.f;
    }
#pragma unroll
    for (int k = 0; k < DD; ++k) {
      const float hk = in[k];
#pragma unroll
      for (int jj = 0; jj < 16; ++jj)
        acc[jj] = fmaf(hk, W[k * DD + c0 + jj], acc[jj]);
    }
  }
  if (n < N) {
    float* o = hnext + ((size_t)n << 6) + c0;
#pragma unroll
    for (int jj = 0; jj < 16; jj += 4)
      *(float4*)(o + jj) =
          make_float4(acc[jj], acc[jj + 1], acc[jj + 2], acc[jj + 3]);
  }
}

// ================= z = relu(h) @ Wg =================
__global__ __launch_bounds__(256) void gemm_relu64(const float* __restrict__ hin,
                                                   const float* __restrict__ W,
                                                   float* __restrict__ out,
                                                   int N) {
  const int lane = threadIdx.x & 63;
  const int wv = threadIdx.x >> 6;
  const int c0 = __builtin_amdgcn_readfirstlane(wv << 4);
  const int n = blockIdx.x * 64 + lane;

  float h[DD];
  if (n < N) {
    const float4* hp = (const float4*)(hin + (size_t)n * DD);
#pragma unroll
    for (int t = 0; t < DD / 4; ++t) {
      float4 v = hp[t];
      v.x = fmaxf(v.x, 0.f); v.y = fmaxf(v.y, 0.f);
      v.z = fmaxf(v.z, 0.f); v.w = fmaxf(v.w, 0.f);
      h[4 * t + 0] = v.x; h[4 * t + 1] = v.y;
      h[4 * t + 2] = v.z; h[4 * t + 3] = v.w;
    }
  } else {
#pragma unroll
    for (int t = 0; t < DD; ++t) h[t] = 0.f;
  }
  float acc[16];
#pragma unroll
  for (int j = 0; j < 16; ++j) acc[j] = 0.f;
#pragma unroll
  for (int k = 0; k < DD; ++k) {
    const float hk = h[k];
#pragma unroll
    for (int j = 0; j < 16; ++j)
      acc[j] = fmaf(hk, W[k * DD + c0 + j], acc[j]);
  }
  if (n < N) {
    float* o = out + ((size_t)n << 6) + c0;
#pragma unroll
    for (int j = 0; j < 16; j += 4)
      *(float4*)(o + j) =
          make_float4(acc[j], acc[j + 1], acc[j + 2], acc[j + 3]);
  }
}

// ================= GAT: el/er per node =================
__global__ __launch_bounds__(256) void el_er_k(
    const float* __restrict__ z, const float* __restrict__ al,
    const float* __restrict__ ar, float* __restrict__ el,
    float* __restrict__ er, int N) {
  int n = blockIdx.x * 4 + (threadIdx.x >> 6);
  int lane = threadIdx.x & 63;
  if (n >= N) return;
  float v = z[(size_t)n * DD + lane];
  float pl = v * al[lane];
  float pr = v * ar[lane];
#pragma unroll
  for (int off = 32; off > 0; off >>= 1) {
    pl += __shfl_down(pl, off);
    pr += __shfl_down(pr, off);
  }
  if (lane == 0) {
    el[n] = pl;
    er[n] = pr;
  }
}

// ================= fused GAT aggregation =================
__global__ __launch_bounds__(256) void gat_fused(
    const float* __restrict__ z, const float* __restrict__ el,
    const float* __restrict__ er, const int* __restrict__ rowptr,
    const int* __restrict__ srcet, float* __restrict__ hg, int N) {
  const int n = blockIdx.x * 4 + (threadIdx.x >> 6);
  const int lane = threadIdx.x & 63;
  const int g = lane >> 4;
  const int t = lane & 15;
  if (n >= N) return;
  const int beg = rowptr[n], end = rowptr[n + 1];
  const float ern = er[n];

  float m = -1e30f, den = 0.f;
  for (int j = beg + lane; j < end; j += 64) {
    const int s = srcet[j] >> 2;
    float x = el[s] + ern;
    x = (x > 0.f) ? x : 0.2f * x;
    if (x > m) {
      den *= __expf(m - x);
      m = x;
    }
    den += __expf(x - m);
  }
#pragma unroll
  for (int off = 1; off < 64; off <<= 1) {
    float mo = __shfl_xor(m, off);
    float dn = __shfl_xor(den, off);
    float M = fmaxf(m, mo);
    den = den * __expf(m - M) + dn * __expf(mo - M);
    m = M;
  }

  float4 num = make_float4(0.f, 0.f, 0.f, 0.f);
  for (int j = beg + g; j < end; j += 4) {
    const int se = srcet[j];
    const int s = se >> 2;
    float x = el[s] + ern;
    x = (x > 0.f) ? x : 0.2f * x;
    const float w = __expf(x - m);
    float4 v = *(const float4*)(z + ((size_t)s << 6) + (t << 2));
    num.x = fmaf(w, v.x, num.x);
    num.y = fmaf(w, v.y, num.y);
    num.z = fmaf(w, v.z, num.z);
    num.w = fmaf(w, v.w, num.w);
  }
#pragma unroll
  for (int off = 16; off <= 32; off <<= 1) {
    num.x += __shfl_xor(num.x, off);
    num.y += __shfl_xor(num.y, off);
    num.z += __shfl_xor(num.z, off);
    num.w += __shfl_xor(num.w, off);
  }
  if (g == 0) {
    const float inv = 1.f / fmaxf(den, 1e-9f);
    float4 o = make_float4(num.x * inv, num.y * inv, num.z * inv, num.w * inv);
    *(float4*)(hg + ((size_t)n << 6) + (t << 2)) = o;
  }
}

// ================= pooled head, two-level =================
__global__ __launch_bounds__(256) void pool_head2(
    const float* __restrict__ hg, const float* __restrict__ Wd,
    const int* __restrict__ gids, float* __restrict__ out, int N, int B) {
  __shared__ float acc[1024];
  for (int i = threadIdx.x; i < B; i += 256) acc[i] = 0.f;
  __syncthreads();

  const int wv = threadIdx.x >> 6;
  const int lane = threadIdx.x & 63;
  const int sub = lane & 3;
  const int idx = lane >> 2;

  const float4 w0 = *(const float4*)(Wd + (sub << 4) + 0);
  const float4 w1 = *(const float4*)(Wd + (sub << 4) + 4);
  const float4 w2 = *(const float4*)(Wd + (sub << 4) + 8);
  const float4 w3 = *(const float4*)(Wd + (sub << 4) + 12);

  const int base0 = blockIdx.x * POOL_NPB;
#pragma unroll 1
  for (int it = 0; it < POOL_NPB / 64; ++it) {
    const int n = base0 + it * 64 + wv * 16 + idx;
    if (n < N) {
      const float* p = hg + ((size_t)n << 6) + (sub << 4);
      const float4 v0 = *(const float4*)(p + 0);
      const float4 v1 = *(const float4*)(p + 4);
      const float4 v2 = *(const float4*)(p + 8);
      const float4 v3 = *(const float4*)(p + 12);
      float s = v0.x * w0.x + v0.y * w0.y + v0.z * w0.z + v0.w * w0.w;
      s = fmaf(v1.x, w1.x, s); s = fmaf(v1.y, w1.y, s);
      s = fmaf(v1.z, w1.z, s); s = fmaf(v1.w, w1.w, s);
      s = fmaf(v2.x, w2.x, s); s = fmaf(v2.y, w2.y, s);
      s = fmaf(v2.z, w2.z, s); s = fmaf(v2.w, w2.w, s);
      s = fmaf(v3.x, w3.x, s); s = fmaf(v3.y, w3.y, s);
      s = fmaf(v3.w, w3.w, s); s = fmaf(v3.z, w3.z, s);
      s += __shfl_xor(s, 1);
      s += __shfl_xor(s, 2);
      if (sub == 0) atomicAdd(&acc[gids[n]], s);
    }
  }
  __syncthreads();
  for (int i = threadIdx.x; i < B; i += 256) {
    const float v = acc[i];
    if (v != 0.f) unsafeAtomicAdd(out + i, v);
  }
}

__global__ void init_out_k(float* out, const float* bd, int n) {
  int i = blockIdx.x * blockDim.x + threadIdx.x;
  if (i < n) out[i] = bd[0];
}

// ================= launch =================
extern "C" void kernel_launch(void* const* d_in, const int* in_sizes, int n_in,
                              void* d_out, int out_size, void* d_ws,
                              size_t ws_size, hipStream_t stream) {
  const float* h0 = (const float*)d_in[0];
  const float* Wrel = (const float*)d_in[1];
  const float* Wloop = (const float*)d_in[2];
  const float* brel = (const float*)d_in[3];
  const float* Wg = (const float*)d_in[4];
  const float* al = (const float*)d_in[5];
  const float* ar = (const float*)d_in[6];
  const float* Wd = (const float*)d_in[7];
  const float* bd = (const float*)d_in[8];
  const int* src = (const int*)d_in[9];
  const int* dst = (const int*)d_in[10];
  const int* et = (const int*)d_in[11];
  const int* gids = (const int*)d_in[12];

  const int N = in_sizes[0] / DD;
  const int E = in_sizes[9];
  const int L = in_sizes[2] / (DD * DD);
  float* out = (float*)d_out;

  // ---- workspace layout ----
  float* wsf = (float*)d_ws;
  float* hA = wsf;                          // N*64
  float* hB = hA + (size_t)N * DD;          // N*64
  float* aggr = hB + (size_t)N * DD;        // N*256
  int* rowptr = (int*)(aggr + (size_t)N * 4 * DD);  // N+1
  int* srcet = rowptr + N + 1;              // E
  float* el = (float*)(srcet + E);          // N
  float* er = el + N;                       // N
  int* chist = (int*)(er + N);              // 256
  int* gcur = chist + 256;                  // 256
  int* cbase = gcur + 256;                  // 256
  unsigned* staging = (unsigned*)aggr;      // E uint, overlays aggr
  float* hg = aggr;                         // overlay: aggr dead after last dense

  dim3 b256(256);
  const int grid_dense = (N + 63) / 64;
  const int grid_n4 = (N + 3) / 4;
  const int nfb = (E + EPB - 1) / EPB;
  const int ncb = (N + 255) >> 8;

  hipLaunchKernelGGL(init_out_k, dim3((out_size + 255) / 256), b256, 0, stream,
                     out, bd, out_size);

  // ---- CSR build (hierarchical fill, (dst,rel)-sorted output) ----
  hipMemsetAsync(chist, 0, 256 * 4, stream);
  hipLaunchKernelGGL(k_hist, dim3(nfb), b256, 0, stream, dst, chist, E);
  hipLaunchKernelGGL(cscan, dim3(1), b256, 0, stream, chist, gcur, cbase);
  hipLaunchKernelGGL(f2_coarse, dim3(nfb), b256, 0, stream, src, dst, et, gcur,
                     staging, E);
  hipLaunchKernelGGL(f3_fine3, dim3(ncb), dim3(1024), 0, stream, staging, cbase,
                     rowptr, srcet, N, E, ncb);

  // ---- RGCN layers ----
  const float* cur = h0;
  float* nxt = hA;
  for (int l = 0; l < L; ++l) {
    hipLaunchKernelGGL(gather_rel, dim3(grid_n4), b256, 0, stream, cur, rowptr,
                       srcet, aggr, N, l > 0 ? 1 : 0);
    hipLaunchKernelGGL(rgcn_dense, dim3(grid_dense), b256, 0, stream, aggr, cur,
                       Wrel + (size_t)l * 4 * DD * DD,
                       Wloop + (size_t)l * DD * DD, brel + (size_t)l * DD, nxt,
                       N, l > 0 ? 1 : 0);
    cur = nxt;
    nxt = (cur == hA) ? hB : hA;
  }

  // ---- GAT ----
  float* zb = nxt;
  hipLaunchKernelGGL(gemm_relu64, dim3(grid_dense), b256, 0, stream, cur, Wg,
                     zb, N);
  hipLaunchKernelGGL(el_er_k, dim3(grid_n4), b256, 0, stream, zb, al, ar, el,
                     er, N);
  hipLaunchKernelGGL(gat_fused, dim3(grid_n4), b256, 0, stream, zb, el, er,
                     rowptr, srcet, hg, N);

  const int grid_pool = (N + POOL_NPB - 1) / POOL_NPB;
  hipLaunchKernelGGL(pool_head2, dim3(grid_pool), b256, 0, stream, hg, Wd, gids,
                     out, N, out_size);
}